// Round 1
// baseline (1051.975 us; speedup 1.0000x reference)
//
#include <hip/hip_runtime.h>

typedef __attribute__((ext_vector_type(8))) short bf16x8;
typedef __attribute__((ext_vector_type(4))) float f32x4;

__device__ __forceinline__ ushort f2b(float x) {
  union { float f; uint u; } v; v.f = x;
  uint u = v.u;
  u += 0x7fffu + ((u >> 16) & 1u);
  return (ushort)(u >> 16);
}
__device__ __forceinline__ float b2f(ushort x) {
  union { uint u; float f; } v; v.u = ((uint)x) << 16;
  return v.f;
}

// async global->LDS, 16B per lane; lds base must be wave-uniform (HW scatters lane*16)
__device__ __forceinline__ void async16(const ushort* g, ushort* l) {
  __builtin_amdgcn_global_load_lds(
      (const __attribute__((address_space(1))) unsigned int*)g,
      (__attribute__((address_space(3))) unsigned int*)l, 16, 0, 0);
}

// ---------------- fp32 -> bf16 conversion ----------------
__global__ __launch_bounds__(256) void cvt_kernel(const float* __restrict__ in,
                                                  ushort* __restrict__ out, int n4) {
  int i = blockIdx.x * 256 + threadIdx.x;
  if (i >= n4) return;
  float4 v = ((const float4*)in)[i];
  ushort4 o;
  o.x = f2b(v.x); o.y = f2b(v.y); o.z = f2b(v.z); o.w = f2b(v.w);
  ((ushort4*)out)[i] = o;
}

// ---------------- RoPE (in-place on bf16) ----------------
__global__ __launch_bounds__(256) void rope_kernel(ushort* __restrict__ q,
                                                   const float* __restrict__ cs,
                                                   const float* __restrict__ sn,
                                                   int n_heads, int total) {
  int idx = blockIdx.x * 256 + threadIdx.x;
  if (idx >= total) return;
  int d = idx & 63;
  int h = (idx >> 6) % n_heads;
  int tok = idx / (64 * n_heads);
  ushort* p = q + (size_t)tok * (n_heads * 128) + h * 128 + d;
  float c = cs[(size_t)tok * 128 + d];
  float s = sn[(size_t)tok * 128 + d];
  float x1 = b2f(p[0]);
  float x2 = b2f(p[64]);
  p[0]  = f2b(x1 * c - x2 * s);
  p[64] = f2b(x2 * c + x1 * s);
}

// ---------------- NT GEMM: C[m,n] = sum_k A[m,k] * B[n,k] ----------------
// 128x128x64 tile, 4 waves (2x2 of 64x64). global_load_lds width-16 staging.
// R3 lesson: acc[4][4] must be fully unroll-indexed or it lives in scratch.
// R4 lesson: the LDS-DMA -> __syncthreads() edge needs an EXPLICIT
// s_waitcnt vmcnt(0); relying on the compiler's barrier drain raced
// intermittently under graph replay (post-timing absmax 0.248).
template <bool OUT_F32>
__global__ __launch_bounds__(256, 1) void gemm_nt(const ushort* __restrict__ A,
                                                  const ushort* __restrict__ B,
                                                  void* __restrict__ Cv,
                                                  int M, int N, int K) {
  __shared__ __align__(16) ushort As[128 * 64];
  __shared__ __align__(16) ushort Bs[128 * 64];
  const int tid = threadIdx.x;
  const int m0 = blockIdx.x * 128;
  const int n0 = blockIdx.y * 128;
  const int wave = tid >> 6, lane = tid & 63;
  const int wm = (wave >> 1) * 64, wn = (wave & 1) * 64;
  const int lr = lane & 15, lq = lane >> 4;

  // staging geometry: issue (i,wave) fills LDS chunk c16 = i*4+wave (8 rows x 64 cols);
  // lane -> row = c16*8 + (lane>>3), slot pos = lane&7, holds global chunk pos^(row&7)
  const int rsub = lane >> 3;     // 0..7
  const int pos = lane & 7;
  const int cg = pos ^ rsub;      // swizzled global 8-ushort chunk index

  // fragment LDS offsets (loop-invariant): read chunk c = ks*4+lq of row,
  // stored at position c ^ (row&7); row&7 == lr&7 here.
  int offA[4][2], offB[4][2];
#pragma unroll
  for (int mi = 0; mi < 4; mi++)
#pragma unroll
    for (int ks = 0; ks < 2; ks++) {
      int c = ks * 4 + lq;
      int sw = (c ^ (lr & 7)) * 8;
      offA[mi][ks] = (wm + mi * 16 + lr) * 64 + sw;
      offB[mi][ks] = (wn + mi * 16 + lr) * 64 + sw;
    }

  f32x4 acc[4][4] = {};

  for (int k0 = 0; k0 < K; k0 += 64) {
#pragma unroll
    for (int i = 0; i < 4; i++) {
      int c16 = i * 4 + wave;
      int row = c16 * 8 + rsub;
      async16(A + (size_t)(m0 + row) * K + k0 + cg * 8, &As[c16 * 512]);
      async16(B + (size_t)(n0 + row) * K + k0 + cg * 8, &Bs[c16 * 512]);
    }
    // explicit drain of the LDS-DMA before the barrier (see R4 note above)
    asm volatile("s_waitcnt vmcnt(0)" ::: "memory");
    __syncthreads();
#pragma unroll
    for (int ks = 0; ks < 2; ks++) {
      bf16x8 af[4], bfv[4];
#pragma unroll
      for (int mi = 0; mi < 4; mi++) af[mi] = *(const bf16x8*)(&As[offA[mi][ks]]);
#pragma unroll
      for (int ni = 0; ni < 4; ni++) bfv[ni] = *(const bf16x8*)(&Bs[offB[ni][ks]]);
#pragma unroll
      for (int mi = 0; mi < 4; mi++)
#pragma unroll
        for (int ni = 0; ni < 4; ni++)
          acc[mi][ni] = __builtin_amdgcn_mfma_f32_16x16x32_bf16(af[mi], bfv[ni], acc[mi][ni], 0, 0, 0);
    }
    __syncthreads();
  }

#pragma unroll
  for (int mi = 0; mi < 4; mi++)
#pragma unroll
    for (int ni = 0; ni < 4; ni++)
#pragma unroll
      for (int r = 0; r < 4; r++) {
        int gm = m0 + wm + mi * 16 + lq * 4 + r;
        int gn = n0 + wn + ni * 16 + lr;
        float v = acc[mi][ni][r];
        if (OUT_F32) ((float*)Cv)[(size_t)gm * N + gn] = v;
        else ((ushort*)Cv)[(size_t)gm * N + gn] = f2b(v);
      }
}

// ---------------- causal flash attention ----------------
// Q: [tok][16*128] bf16 (rope'd), K/V: [tok][4*128] bf16, O: [tok][16*128] bf16
// grid: (qtile=16, head=16, batch=4), 256 threads = 4 waves, wave owns 32 q rows.
// R5 changes vs previous version:
//   1. Ps aliased onto Ks (union): Ks is dead after the QK^T reads, so P can
//      reuse its LDS at the cost of one extra barrier. LDS 54.2K -> 36.9K,
//      occupancy 2 -> 4 blocks/CU. Kernel is latency-bound (MfmaUtil 8%,
//      VALUBusy 30%, HBM 4%) so cross-block overlap is the lever.
//   2. __launch_bounds__(256, 4): pin VGPR <= 128 so 16 waves/CU are resident.
//   3. qt permuted by (xi*5 + h) & 15: causal work per tile spans 2..32
//      j-iterations; with the grid now exactly resident (1024 blocks = 4/CU),
//      decorrelating heavy tiles across CUs sets the tail.
//   4. causal mask VALU only on diagonal tiles (j >= 2*qt); for j < 2*qt the
//      whole 64-col tile is strictly below the diagonal.
__global__ __launch_bounds__(256, 4) void attn_kernel(const ushort* __restrict__ Q,
                                                   const ushort* __restrict__ Kb,
                                                   const ushort* __restrict__ Vb,
                                                   ushort* __restrict__ O) {
  constexpr int T = 2048;
  // union region: Ks[64][136] (17408B) / Ps[128][72] (18432B)
  __shared__ __align__(16) ushort UKP[128 * 72];
  __shared__ __align__(16) ushort Vts[128][72];  // V^T tile: 128 d x 64 kv (padded)
  ushort (* __restrict__ Ks)[136] = (ushort (*)[136])UKP;
  ushort (* __restrict__ Ps)[72]  = (ushort (*)[72])UKP;

  const int xi = blockIdx.x, h = blockIdx.y, b = blockIdx.z;
  const int qt = (xi * 5 + h) & 15;  // bijective in xi for fixed h: gcd(5,16)=1
  const int kvh = h >> 2;
  const int tid = threadIdx.x, wave = tid >> 6, lane = tid & 63;
  const int lr = lane & 15, lq = lane >> 4;
  const int q0 = qt * 128;
  const size_t qbase = (size_t)b * T * 2048 + (size_t)h * 128;
  const size_t kvbase = (size_t)b * T * 512 + (size_t)kvh * 128;

  // Q fragments in registers: wave rows [wave*32, wave*32+32)
  bf16x8 qf[2][4];
#pragma unroll
  for (int mi = 0; mi < 2; mi++)
#pragma unroll
    for (int kx = 0; kx < 4; kx++) {
      int row = q0 + wave * 32 + mi * 16 + lr;
      qf[mi][kx] = *(const bf16x8*)(Q + qbase + (size_t)row * 2048 + kx * 32 + lq * 8);
    }

  float mstate[2][4], lstate[2][4];
  f32x4 oacc[2][8] = {};
#pragma unroll
  for (int mi = 0; mi < 2; mi++)
#pragma unroll
    for (int r = 0; r < 4; r++) { mstate[mi][r] = -__builtin_inff(); lstate[mi][r] = 0.f; }

  const float SC = 0.08838834764831845f * 1.4426950408889634f; // 1/sqrt(128) * log2(e)
  const int jmax = 2 * qt + 1;

  const int krow = tid >> 4, kc = (tid & 15) * 8;     // K staging
  const int vr = tid >> 2, vd0 = (tid & 3) * 2;       // V staging (transposed)

  for (int j = 0; j <= jmax; j++) {
    const int kv0 = j * 64;
    // stage K tile (coalesced)
#pragma unroll
    for (int i = 0; i < 4; i++) {
      int r = krow + i * 16;
      uint4 v = *(const uint4*)(Kb + kvbase + (size_t)(kv0 + r) * 512 + kc);
      *(uint4*)(&Ks[r][kc]) = v;
    }
    // stage V transposed
#pragma unroll
    for (int dd = 0; dd < 16; dd++) {
      int d = vd0 + dd * 8;
      uint v = *(const uint*)(Vb + kvbase + (size_t)(kv0 + vr) * 512 + d);
      Vts[d][vr] = (ushort)(v & 0xffffu);
      Vts[d + 1][vr] = (ushort)(v >> 16);
    }
    __syncthreads();

    // S = Q * K^T (32 x 64 per wave)
    f32x4 sacc[2][4] = {};
#pragma unroll
    for (int kx = 0; kx < 4; kx++) {
      bf16x8 kf[4];
#pragma unroll
      for (int ni = 0; ni < 4; ni++)
        kf[ni] = *(const bf16x8*)(&Ks[ni * 16 + lr][kx * 32 + lq * 8]);
#pragma unroll
      for (int mi = 0; mi < 2; mi++)
#pragma unroll
        for (int ni = 0; ni < 4; ni++)
          sacc[mi][ni] = __builtin_amdgcn_mfma_f32_16x16x32_bf16(qf[mi][kx], kf[ni], sacc[mi][ni], 0, 0, 0);
    }

    // Ks is dead from here; barrier so P can reuse its LDS (union).
    __syncthreads();

    const bool domask = (j >= 2 * qt);  // only diagonal tiles can mask

    // online softmax per wave-owned rows
#pragma unroll
    for (int mi = 0; mi < 2; mi++) {
      float rmax[4];
#pragma unroll
      for (int r = 0; r < 4; r++) {
        float mx = -__builtin_inff();
        if (domask) {
          int grow = q0 + wave * 32 + mi * 16 + lq * 4 + r;
#pragma unroll
          for (int ni = 0; ni < 4; ni++) {
            float s = sacc[mi][ni][r] * SC;
            int gcol = kv0 + ni * 16 + lr;
            if (gcol > grow) s = -__builtin_inff();
            sacc[mi][ni][r] = s;
            mx = fmaxf(mx, s);
          }
        } else {
#pragma unroll
          for (int ni = 0; ni < 4; ni++) {
            float s = sacc[mi][ni][r] * SC;
            sacc[mi][ni][r] = s;
            mx = fmaxf(mx, s);
          }
        }
        mx = fmaxf(mx, __shfl_xor(mx, 1));
        mx = fmaxf(mx, __shfl_xor(mx, 2));
        mx = fmaxf(mx, __shfl_xor(mx, 4));
        mx = fmaxf(mx, __shfl_xor(mx, 8));
        rmax[r] = mx;
      }
#pragma unroll
      for (int r = 0; r < 4; r++) {
        float mold = mstate[mi][r];
        float mnew = fmaxf(mold, rmax[r]);
        float alpha = exp2f(mold - mnew);
        float rs = 0.f;
#pragma unroll
        for (int ni = 0; ni < 4; ni++) {
          float p = exp2f(sacc[mi][ni][r] - mnew);
          sacc[mi][ni][r] = p;
          rs += p;
        }
        rs += __shfl_xor(rs, 1); rs += __shfl_xor(rs, 2);
        rs += __shfl_xor(rs, 4); rs += __shfl_xor(rs, 8);
        lstate[mi][r] = lstate[mi][r] * alpha + rs;
        mstate[mi][r] = mnew;
#pragma unroll
        for (int ni = 0; ni < 8; ni++) oacc[mi][ni][r] *= alpha;
      }
      // P -> LDS (C/D layout write); wave-private rows, read back by same wave
#pragma unroll
      for (int ni = 0; ni < 4; ni++)
#pragma unroll
        for (int r = 0; r < 4; r++)
          Ps[wave * 32 + mi * 16 + lq * 4 + r][ni * 16 + lr] = f2b(sacc[mi][ni][r]);
    }

    // O += P * V  (P: 32x64 A-layout from LDS, V^T for B operand)
#pragma unroll
    for (int k2 = 0; k2 < 2; k2++) {
      bf16x8 pf[2];
#pragma unroll
      for (int mi = 0; mi < 2; mi++)
        pf[mi] = *(const bf16x8*)(&Ps[wave * 32 + mi * 16 + lr][k2 * 32 + lq * 8]);
#pragma unroll
      for (int ni = 0; ni < 8; ni++) {
        bf16x8 vf = *(const bf16x8*)(&Vts[ni * 16 + lr][k2 * 32 + lq * 8]);
#pragma unroll
        for (int mi = 0; mi < 2; mi++)
          oacc[mi][ni] = __builtin_amdgcn_mfma_f32_16x16x32_bf16(pf[mi], vf, oacc[mi][ni], 0, 0, 0);
      }
    }
    __syncthreads();
  }

  // epilogue: O /= l, write bf16
#pragma unroll
  for (int mi = 0; mi < 2; mi++)
#pragma unroll
    for (int r = 0; r < 4; r++) {
      float inv = 1.0f / lstate[mi][r];
      int grow = q0 + wave * 32 + mi * 16 + lq * 4 + r;
      size_t base = ((size_t)b * T + grow) * 2048 + (size_t)h * 128;
#pragma unroll
      for (int ni = 0; ni < 8; ni++)
        O[base + ni * 16 + lr] = f2b(oacc[mi][ni][r] * inv);
    }
}

// ---------------- launcher ----------------
extern "C" void kernel_launch(void* const* d_in, const int* in_sizes, int n_in,
                              void* d_out, int out_size, void* d_ws, size_t ws_size,
                              hipStream_t stream) {
  const float* hs   = (const float*)d_in[0];
  const float* cosp = (const float*)d_in[1];
  const float* sinp = (const float*)d_in[2];
  const float* wq   = (const float*)d_in[3];
  const float* wk   = (const float*)d_in[4];
  const float* wv   = (const float*)d_in[5];
  const float* wo   = (const float*)d_in[6];
  float* out = (float*)d_out;

  char* p = (char*)d_ws;
  ushort* hs_b = (ushort*)p; p += (size_t)8192 * 2048 * 2;
  ushort* q_b  = (ushort*)p; p += (size_t)8192 * 2048 * 2;
  ushort* k_b  = (ushort*)p; p += (size_t)8192 * 512 * 2;
  ushort* v_b  = (ushort*)p; p += (size_t)8192 * 512 * 2;
  ushort* o_b  = (ushort*)p; p += (size_t)8192 * 2048 * 2;
  ushort* wq_b = (ushort*)p; p += (size_t)2048 * 2048 * 2;
  ushort* wk_b = (ushort*)p; p += (size_t)512 * 2048 * 2;
  ushort* wv_b = (ushort*)p; p += (size_t)512 * 2048 * 2;
  ushort* wo_b = (ushort*)p; p += (size_t)2048 * 2048 * 2;

  // conversions
  cvt_kernel<<<16384, 256, 0, stream>>>(hs, hs_b, 4194304);
  cvt_kernel<<<4096, 256, 0, stream>>>(wq, wq_b, 1048576);
  cvt_kernel<<<1024, 256, 0, stream>>>(wk, wk_b, 262144);
  cvt_kernel<<<1024, 256, 0, stream>>>(wv, wv_b, 262144);
  cvt_kernel<<<4096, 256, 0, stream>>>(wo, wo_b, 1048576);

  // projections
  gemm_nt<false><<<dim3(64, 16), 256, 0, stream>>>(hs_b, wq_b, q_b, 8192, 2048, 2048);
  gemm_nt<false><<<dim3(64, 4), 256, 0, stream>>>(hs_b, wk_b, k_b, 8192, 512, 2048);
  gemm_nt<false><<<dim3(64, 4), 256, 0, stream>>>(hs_b, wv_b, v_b, 8192, 512, 2048);

  // rope
  rope_kernel<<<32768, 256, 0, stream>>>(q_b, cosp, sinp, 16, 8388608);
  rope_kernel<<<8192, 256, 0, stream>>>(k_b, cosp, sinp, 4, 2097152);

  // attention
  attn_kernel<<<dim3(16, 16, 4), 256, 0, stream>>>(q_b, k_b, v_b, o_b);

  // output projection (fp32 out)
  gemm_nt<true><<<dim3(64, 16), 256, 0, stream>>>(o_b, wo_b, out, 8192, 2048, 2048);
}

// Round 2
// 845.688 us; speedup vs baseline: 1.2439x; 1.2439x over previous
//
#include <hip/hip_runtime.h>

typedef __attribute__((ext_vector_type(8))) short bf16x8;
typedef __attribute__((ext_vector_type(4))) float f32x4;

__device__ __forceinline__ ushort f2b(float x) {
  union { float f; uint u; } v; v.f = x;
  uint u = v.u;
  u += 0x7fffu + ((u >> 16) & 1u);
  return (ushort)(u >> 16);
}
__device__ __forceinline__ float b2f(ushort x) {
  union { uint u; float f; } v; v.u = ((uint)x) << 16;
  return v.f;
}

// async global->LDS, 16B per lane; lds base must be wave-uniform (HW scatters lane*16)
__device__ __forceinline__ void async16(const ushort* g, ushort* l) {
  __builtin_amdgcn_global_load_lds(
      (const __attribute__((address_space(1))) unsigned int*)g,
      (__attribute__((address_space(3))) unsigned int*)l, 16, 0, 0);
}

// ---------------- fp32 -> bf16 conversion ----------------
__global__ __launch_bounds__(256) void cvt_kernel(const float* __restrict__ in,
                                                  ushort* __restrict__ out, int n4) {
  int i = blockIdx.x * 256 + threadIdx.x;
  if (i >= n4) return;
  float4 v = ((const float4*)in)[i];
  ushort4 o;
  o.x = f2b(v.x); o.y = f2b(v.y); o.z = f2b(v.z); o.w = f2b(v.w);
  ((ushort4*)out)[i] = o;
}

// ---------------- RoPE (in-place on bf16) ----------------
__global__ __launch_bounds__(256) void rope_kernel(ushort* __restrict__ q,
                                                   const float* __restrict__ cs,
                                                   const float* __restrict__ sn,
                                                   int n_heads, int total) {
  int idx = blockIdx.x * 256 + threadIdx.x;
  if (idx >= total) return;
  int d = idx & 63;
  int h = (idx >> 6) % n_heads;
  int tok = idx / (64 * n_heads);
  ushort* p = q + (size_t)tok * (n_heads * 128) + h * 128 + d;
  float c = cs[(size_t)tok * 128 + d];
  float s = sn[(size_t)tok * 128 + d];
  float x1 = b2f(p[0]);
  float x2 = b2f(p[64]);
  p[0]  = f2b(x1 * c - x2 * s);
  p[64] = f2b(x2 * c + x1 * s);
}

// ---------------- NT GEMM: C[m,n] = sum_k A[m,k] * B[n,k] ----------------
// 128x128x64 tile, 4 waves (2x2 of 64x64). global_load_lds width-16 staging.
// R3 lesson: acc[4][4] must be fully unroll-indexed or it lives in scratch.
// R4 lesson: the LDS-DMA -> __syncthreads() edge needs an EXPLICIT
// s_waitcnt vmcnt(0); relying on the compiler's barrier drain raced
// intermittently under graph replay (post-timing absmax 0.248).
template <bool OUT_F32>
__global__ __launch_bounds__(256, 1) void gemm_nt(const ushort* __restrict__ A,
                                                  const ushort* __restrict__ B,
                                                  void* __restrict__ Cv,
                                                  int M, int N, int K) {
  __shared__ __align__(16) ushort As[128 * 64];
  __shared__ __align__(16) ushort Bs[128 * 64];
  const int tid = threadIdx.x;
  const int m0 = blockIdx.x * 128;
  const int n0 = blockIdx.y * 128;
  const int wave = tid >> 6, lane = tid & 63;
  const int wm = (wave >> 1) * 64, wn = (wave & 1) * 64;
  const int lr = lane & 15, lq = lane >> 4;

  // staging geometry: issue (i,wave) fills LDS chunk c16 = i*4+wave (8 rows x 64 cols);
  // lane -> row = c16*8 + (lane>>3), slot pos = lane&7, holds global chunk pos^(row&7)
  const int rsub = lane >> 3;     // 0..7
  const int pos = lane & 7;
  const int cg = pos ^ rsub;      // swizzled global 8-ushort chunk index

  // fragment LDS offsets (loop-invariant): read chunk c = ks*4+lq of row,
  // stored at position c ^ (row&7); row&7 == lr&7 here.
  int offA[4][2], offB[4][2];
#pragma unroll
  for (int mi = 0; mi < 4; mi++)
#pragma unroll
    for (int ks = 0; ks < 2; ks++) {
      int c = ks * 4 + lq;
      int sw = (c ^ (lr & 7)) * 8;
      offA[mi][ks] = (wm + mi * 16 + lr) * 64 + sw;
      offB[mi][ks] = (wn + mi * 16 + lr) * 64 + sw;
    }

  f32x4 acc[4][4] = {};

  for (int k0 = 0; k0 < K; k0 += 64) {
#pragma unroll
    for (int i = 0; i < 4; i++) {
      int c16 = i * 4 + wave;
      int row = c16 * 8 + rsub;
      async16(A + (size_t)(m0 + row) * K + k0 + cg * 8, &As[c16 * 512]);
      async16(B + (size_t)(n0 + row) * K + k0 + cg * 8, &Bs[c16 * 512]);
    }
    // explicit drain of the LDS-DMA before the barrier (see R4 note above)
    asm volatile("s_waitcnt vmcnt(0)" ::: "memory");
    __syncthreads();
#pragma unroll
    for (int ks = 0; ks < 2; ks++) {
      bf16x8 af[4], bfv[4];
#pragma unroll
      for (int mi = 0; mi < 4; mi++) af[mi] = *(const bf16x8*)(&As[offA[mi][ks]]);
#pragma unroll
      for (int ni = 0; ni < 4; ni++) bfv[ni] = *(const bf16x8*)(&Bs[offB[ni][ks]]);
#pragma unroll
      for (int mi = 0; mi < 4; mi++)
#pragma unroll
        for (int ni = 0; ni < 4; ni++)
          acc[mi][ni] = __builtin_amdgcn_mfma_f32_16x16x32_bf16(af[mi], bfv[ni], acc[mi][ni], 0, 0, 0);
    }
    __syncthreads();
  }

#pragma unroll
  for (int mi = 0; mi < 4; mi++)
#pragma unroll
    for (int ni = 0; ni < 4; ni++)
#pragma unroll
      for (int r = 0; r < 4; r++) {
        int gm = m0 + wm + mi * 16 + lq * 4 + r;
        int gn = n0 + wn + ni * 16 + lr;
        float v = acc[mi][ni][r];
        if (OUT_F32) ((float*)Cv)[(size_t)gm * N + gn] = v;
        else ((ushort*)Cv)[(size_t)gm * N + gn] = f2b(v);
      }
}

// ---------------- causal flash attention ----------------
// Q: [tok][16*128] bf16 (rope'd), K/V: [tok][4*128] bf16, O: [tok][16*128] bf16
// grid: (qtile=16, head=16, batch=4), 256 threads = 4 waves, wave owns 32 q rows.
// R5: Ks/Ps LDS union (54.2K -> 36.9K), qt permutation, diagonal-only masking.
// R6 lesson: __launch_bounds__(256, 4) forced VGPR 128 -> 64 and spilled the
// accumulator state: FETCH+WRITE went 0.10 GB -> 1.26 GB (scratch traffic),
// dur 355 -> 628 us. The kernel NEEDS ~128 VGPRs live. With (256,1) the
// allocator lands exactly at 128, which already gives 4 waves/SIMD; combined
// with the 36.9K LDS both limits agree at 4 blocks/CU — the occupancy win
// without the spill.
__global__ __launch_bounds__(256, 1) void attn_kernel(const ushort* __restrict__ Q,
                                                   const ushort* __restrict__ Kb,
                                                   const ushort* __restrict__ Vb,
                                                   ushort* __restrict__ O) {
  constexpr int T = 2048;
  // union region: Ks[64][136] (17408B) / Ps[128][72] (18432B)
  __shared__ __align__(16) ushort UKP[128 * 72];
  __shared__ __align__(16) ushort Vts[128][72];  // V^T tile: 128 d x 64 kv (padded)
  ushort (* __restrict__ Ks)[136] = (ushort (*)[136])UKP;
  ushort (* __restrict__ Ps)[72]  = (ushort (*)[72])UKP;

  const int xi = blockIdx.x, h = blockIdx.y, b = blockIdx.z;
  const int qt = (xi * 5 + h) & 15;  // bijective in xi for fixed h: gcd(5,16)=1
  const int kvh = h >> 2;
  const int tid = threadIdx.x, wave = tid >> 6, lane = tid & 63;
  const int lr = lane & 15, lq = lane >> 4;
  const int q0 = qt * 128;
  const size_t qbase = (size_t)b * T * 2048 + (size_t)h * 128;
  const size_t kvbase = (size_t)b * T * 512 + (size_t)kvh * 128;

  // Q fragments in registers: wave rows [wave*32, wave*32+32)
  bf16x8 qf[2][4];
#pragma unroll
  for (int mi = 0; mi < 2; mi++)
#pragma unroll
    for (int kx = 0; kx < 4; kx++) {
      int row = q0 + wave * 32 + mi * 16 + lr;
      qf[mi][kx] = *(const bf16x8*)(Q + qbase + (size_t)row * 2048 + kx * 32 + lq * 8);
    }

  float mstate[2][4], lstate[2][4];
  f32x4 oacc[2][8] = {};
#pragma unroll
  for (int mi = 0; mi < 2; mi++)
#pragma unroll
    for (int r = 0; r < 4; r++) { mstate[mi][r] = -__builtin_inff(); lstate[mi][r] = 0.f; }

  const float SC = 0.08838834764831845f * 1.4426950408889634f; // 1/sqrt(128) * log2(e)
  const int jmax = 2 * qt + 1;

  const int krow = tid >> 4, kc = (tid & 15) * 8;     // K staging
  const int vr = tid >> 2, vd0 = (tid & 3) * 2;       // V staging (transposed)

  for (int j = 0; j <= jmax; j++) {
    const int kv0 = j * 64;
    // stage K tile (coalesced)
#pragma unroll
    for (int i = 0; i < 4; i++) {
      int r = krow + i * 16;
      uint4 v = *(const uint4*)(Kb + kvbase + (size_t)(kv0 + r) * 512 + kc);
      *(uint4*)(&Ks[r][kc]) = v;
    }
    // stage V transposed
#pragma unroll
    for (int dd = 0; dd < 16; dd++) {
      int d = vd0 + dd * 8;
      uint v = *(const uint*)(Vb + kvbase + (size_t)(kv0 + vr) * 512 + d);
      Vts[d][vr] = (ushort)(v & 0xffffu);
      Vts[d + 1][vr] = (ushort)(v >> 16);
    }
    __syncthreads();

    // S = Q * K^T (32 x 64 per wave)
    f32x4 sacc[2][4] = {};
#pragma unroll
    for (int kx = 0; kx < 4; kx++) {
      bf16x8 kf[4];
#pragma unroll
      for (int ni = 0; ni < 4; ni++)
        kf[ni] = *(const bf16x8*)(&Ks[ni * 16 + lr][kx * 32 + lq * 8]);
#pragma unroll
      for (int mi = 0; mi < 2; mi++)
#pragma unroll
        for (int ni = 0; ni < 4; ni++)
          sacc[mi][ni] = __builtin_amdgcn_mfma_f32_16x16x32_bf16(qf[mi][kx], kf[ni], sacc[mi][ni], 0, 0, 0);
    }

    // Ks is dead from here; barrier so P can reuse its LDS (union).
    __syncthreads();

    const bool domask = (j >= 2 * qt);  // only diagonal tiles can mask

    // online softmax per wave-owned rows
#pragma unroll
    for (int mi = 0; mi < 2; mi++) {
      float rmax[4];
#pragma unroll
      for (int r = 0; r < 4; r++) {
        float mx = -__builtin_inff();
        if (domask) {
          int grow = q0 + wave * 32 + mi * 16 + lq * 4 + r;
#pragma unroll
          for (int ni = 0; ni < 4; ni++) {
            float s = sacc[mi][ni][r] * SC;
            int gcol = kv0 + ni * 16 + lr;
            if (gcol > grow) s = -__builtin_inff();
            sacc[mi][ni][r] = s;
            mx = fmaxf(mx, s);
          }
        } else {
#pragma unroll
          for (int ni = 0; ni < 4; ni++) {
            float s = sacc[mi][ni][r] * SC;
            sacc[mi][ni][r] = s;
            mx = fmaxf(mx, s);
          }
        }
        mx = fmaxf(mx, __shfl_xor(mx, 1));
        mx = fmaxf(mx, __shfl_xor(mx, 2));
        mx = fmaxf(mx, __shfl_xor(mx, 4));
        mx = fmaxf(mx, __shfl_xor(mx, 8));
        rmax[r] = mx;
      }
#pragma unroll
      for (int r = 0; r < 4; r++) {
        float mold = mstate[mi][r];
        float mnew = fmaxf(mold, rmax[r]);
        float alpha = exp2f(mold - mnew);
        float rs = 0.f;
#pragma unroll
        for (int ni = 0; ni < 4; ni++) {
          float p = exp2f(sacc[mi][ni][r] - mnew);
          sacc[mi][ni][r] = p;
          rs += p;
        }
        rs += __shfl_xor(rs, 1); rs += __shfl_xor(rs, 2);
        rs += __shfl_xor(rs, 4); rs += __shfl_xor(rs, 8);
        lstate[mi][r] = lstate[mi][r] * alpha + rs;
        mstate[mi][r] = mnew;
#pragma unroll
        for (int ni = 0; ni < 8; ni++) oacc[mi][ni][r] *= alpha;
      }
      // P -> LDS (C/D layout write); wave-private rows, read back by same wave
#pragma unroll
      for (int ni = 0; ni < 4; ni++)
#pragma unroll
        for (int r = 0; r < 4; r++)
          Ps[wave * 32 + mi * 16 + lq * 4 + r][ni * 16 + lr] = f2b(sacc[mi][ni][r]);
    }

    // O += P * V  (P: 32x64 A-layout from LDS, V^T for B operand)
#pragma unroll
    for (int k2 = 0; k2 < 2; k2++) {
      bf16x8 pf[2];
#pragma unroll
      for (int mi = 0; mi < 2; mi++)
        pf[mi] = *(const bf16x8*)(&Ps[wave * 32 + mi * 16 + lr][k2 * 32 + lq * 8]);
#pragma unroll
      for (int ni = 0; ni < 8; ni++) {
        bf16x8 vf = *(const bf16x8*)(&Vts[ni * 16 + lr][k2 * 32 + lq * 8]);
#pragma unroll
        for (int mi = 0; mi < 2; mi++)
          oacc[mi][ni] = __builtin_amdgcn_mfma_f32_16x16x32_bf16(pf[mi], vf, oacc[mi][ni], 0, 0, 0);
      }
    }
    __syncthreads();
  }

  // epilogue: O /= l, write bf16
#pragma unroll
  for (int mi = 0; mi < 2; mi++)
#pragma unroll
    for (int r = 0; r < 4; r++) {
      float inv = 1.0f / lstate[mi][r];
      int grow = q0 + wave * 32 + mi * 16 + lq * 4 + r;
      size_t base = ((size_t)b * T + grow) * 2048 + (size_t)h * 128;
#pragma unroll
      for (int ni = 0; ni < 8; ni++)
        O[base + ni * 16 + lr] = f2b(oacc[mi][ni][r] * inv);
    }
}

// ---------------- launcher ----------------
extern "C" void kernel_launch(void* const* d_in, const int* in_sizes, int n_in,
                              void* d_out, int out_size, void* d_ws, size_t ws_size,
                              hipStream_t stream) {
  const float* hs   = (const float*)d_in[0];
  const float* cosp = (const float*)d_in[1];
  const float* sinp = (const float*)d_in[2];
  const float* wq   = (const float*)d_in[3];
  const float* wk   = (const float*)d_in[4];
  const float* wv   = (const float*)d_in[5];
  const float* wo   = (const float*)d_in[6];
  float* out = (float*)d_out;

  char* p = (char*)d_ws;
  ushort* hs_b = (ushort*)p; p += (size_t)8192 * 2048 * 2;
  ushort* q_b  = (ushort*)p; p += (size_t)8192 * 2048 * 2;
  ushort* k_b  = (ushort*)p; p += (size_t)8192 * 512 * 2;
  ushort* v_b  = (ushort*)p; p += (size_t)8192 * 512 * 2;
  ushort* o_b  = (ushort*)p; p += (size_t)8192 * 2048 * 2;
  ushort* wq_b = (ushort*)p; p += (size_t)2048 * 2048 * 2;
  ushort* wk_b = (ushort*)p; p += (size_t)512 * 2048 * 2;
  ushort* wv_b = (ushort*)p; p += (size_t)512 * 2048 * 2;
  ushort* wo_b = (ushort*)p; p += (size_t)2048 * 2048 * 2;

  // conversions
  cvt_kernel<<<16384, 256, 0, stream>>>(hs, hs_b, 4194304);
  cvt_kernel<<<4096, 256, 0, stream>>>(wq, wq_b, 1048576);
  cvt_kernel<<<1024, 256, 0, stream>>>(wk, wk_b, 262144);
  cvt_kernel<<<1024, 256, 0, stream>>>(wv, wv_b, 262144);
  cvt_kernel<<<4096, 256, 0, stream>>>(wo, wo_b, 1048576);

  // projections
  gemm_nt<false><<<dim3(64, 16), 256, 0, stream>>>(hs_b, wq_b, q_b, 8192, 2048, 2048);
  gemm_nt<false><<<dim3(64, 4), 256, 0, stream>>>(hs_b, wk_b, k_b, 8192, 512, 2048);
  gemm_nt<false><<<dim3(64, 4), 256, 0, stream>>>(hs_b, wv_b, v_b, 8192, 512, 2048);

  // rope
  rope_kernel<<<32768, 256, 0, stream>>>(q_b, cosp, sinp, 16, 8388608);
  rope_kernel<<<8192, 256, 0, stream>>>(k_b, cosp, sinp, 4, 2097152);

  // attention
  attn_kernel<<<dim3(16, 16, 4), 256, 0, stream>>>(q_b, k_b, v_b, o_b);

  // output projection (fp32 out)
  gemm_nt<true><<<dim3(64, 16), 256, 0, stream>>>(o_b, wo_b, out, 8192, 2048, 2048);
}

// Round 3
// 745.961 us; speedup vs baseline: 1.4102x; 1.1337x over previous
//
#include <hip/hip_runtime.h>

typedef __attribute__((ext_vector_type(8))) short bf16x8;
typedef __attribute__((ext_vector_type(4))) float f32x4;

__device__ __forceinline__ ushort f2b(float x) {
  union { float f; uint u; } v; v.f = x;
  uint u = v.u;
  u += 0x7fffu + ((u >> 16) & 1u);
  return (ushort)(u >> 16);
}
__device__ __forceinline__ float b2f(ushort x) {
  union { uint u; float f; } v; v.u = ((uint)x) << 16;
  return v.f;
}

// async global->LDS, 16B per lane; lds base must be wave-uniform (HW scatters lane*16)
__device__ __forceinline__ void async16(const ushort* g, ushort* l) {
  __builtin_amdgcn_global_load_lds(
      (const __attribute__((address_space(1))) unsigned int*)g,
      (__attribute__((address_space(3))) unsigned int*)l, 16, 0, 0);
}

// ---------------- fp32 -> bf16 conversion ----------------
__global__ __launch_bounds__(256) void cvt_kernel(const float* __restrict__ in,
                                                  ushort* __restrict__ out, int n4) {
  int i = blockIdx.x * 256 + threadIdx.x;
  if (i >= n4) return;
  float4 v = ((const float4*)in)[i];
  ushort4 o;
  o.x = f2b(v.x); o.y = f2b(v.y); o.z = f2b(v.z); o.w = f2b(v.w);
  ((ushort4*)out)[i] = o;
}

// ---------------- RoPE (in-place on bf16) ----------------
__global__ __launch_bounds__(256) void rope_kernel(ushort* __restrict__ q,
                                                   const float* __restrict__ cs,
                                                   const float* __restrict__ sn,
                                                   int n_heads, int total) {
  int idx = blockIdx.x * 256 + threadIdx.x;
  if (idx >= total) return;
  int d = idx & 63;
  int h = (idx >> 6) % n_heads;
  int tok = idx / (64 * n_heads);
  ushort* p = q + (size_t)tok * (n_heads * 128) + h * 128 + d;
  float c = cs[(size_t)tok * 128 + d];
  float s = sn[(size_t)tok * 128 + d];
  float x1 = b2f(p[0]);
  float x2 = b2f(p[64]);
  p[0]  = f2b(x1 * c - x2 * s);
  p[64] = f2b(x2 * c + x1 * s);
}

// ---------------- NT GEMM: C[m,n] = sum_k A[m,k] * B[n,k] ----------------
// 128x128x64 tile, 4 waves (2x2 of 64x64). global_load_lds width-16 staging.
// R3 lesson: acc[4][4] must be fully unroll-indexed or it lives in scratch.
// R4 lesson: the LDS-DMA -> __syncthreads() edge needs an EXPLICIT
// s_waitcnt vmcnt(0); relying on the compiler's barrier drain raced
// intermittently under graph replay (post-timing absmax 0.248).
template <bool OUT_F32>
__global__ __launch_bounds__(256, 1) void gemm_nt(const ushort* __restrict__ A,
                                                  const ushort* __restrict__ B,
                                                  void* __restrict__ Cv,
                                                  int M, int N, int K) {
  __shared__ __align__(16) ushort As[128 * 64];
  __shared__ __align__(16) ushort Bs[128 * 64];
  const int tid = threadIdx.x;
  const int m0 = blockIdx.x * 128;
  const int n0 = blockIdx.y * 128;
  const int wave = tid >> 6, lane = tid & 63;
  const int wm = (wave >> 1) * 64, wn = (wave & 1) * 64;
  const int lr = lane & 15, lq = lane >> 4;

  // staging geometry: issue (i,wave) fills LDS chunk c16 = i*4+wave (8 rows x 64 cols);
  // lane -> row = c16*8 + (lane>>3), slot pos = lane&7, holds global chunk pos^(row&7)
  const int rsub = lane >> 3;     // 0..7
  const int pos = lane & 7;
  const int cg = pos ^ rsub;      // swizzled global 8-ushort chunk index

  // fragment LDS offsets (loop-invariant): read chunk c = ks*4+lq of row,
  // stored at position c ^ (row&7); row&7 == lr&7 here.
  int offA[4][2], offB[4][2];
#pragma unroll
  for (int mi = 0; mi < 4; mi++)
#pragma unroll
    for (int ks = 0; ks < 2; ks++) {
      int c = ks * 4 + lq;
      int sw = (c ^ (lr & 7)) * 8;
      offA[mi][ks] = (wm + mi * 16 + lr) * 64 + sw;
      offB[mi][ks] = (wn + mi * 16 + lr) * 64 + sw;
    }

  f32x4 acc[4][4] = {};

  for (int k0 = 0; k0 < K; k0 += 64) {
#pragma unroll
    for (int i = 0; i < 4; i++) {
      int c16 = i * 4 + wave;
      int row = c16 * 8 + rsub;
      async16(A + (size_t)(m0 + row) * K + k0 + cg * 8, &As[c16 * 512]);
      async16(B + (size_t)(n0 + row) * K + k0 + cg * 8, &Bs[c16 * 512]);
    }
    // explicit drain of the LDS-DMA before the barrier (see R4 note above)
    asm volatile("s_waitcnt vmcnt(0)" ::: "memory");
    __syncthreads();
#pragma unroll
    for (int ks = 0; ks < 2; ks++) {
      bf16x8 af[4], bfv[4];
#pragma unroll
      for (int mi = 0; mi < 4; mi++) af[mi] = *(const bf16x8*)(&As[offA[mi][ks]]);
#pragma unroll
      for (int ni = 0; ni < 4; ni++) bfv[ni] = *(const bf16x8*)(&Bs[offB[ni][ks]]);
#pragma unroll
      for (int mi = 0; mi < 4; mi++)
#pragma unroll
        for (int ni = 0; ni < 4; ni++)
          acc[mi][ni] = __builtin_amdgcn_mfma_f32_16x16x32_bf16(af[mi], bfv[ni], acc[mi][ni], 0, 0, 0);
    }
    __syncthreads();
  }

#pragma unroll
  for (int mi = 0; mi < 4; mi++)
#pragma unroll
    for (int ni = 0; ni < 4; ni++)
#pragma unroll
      for (int r = 0; r < 4; r++) {
        int gm = m0 + wm + mi * 16 + lq * 4 + r;
        int gn = n0 + wn + ni * 16 + lr;
        float v = acc[mi][ni][r];
        if (OUT_F32) ((float*)Cv)[(size_t)gm * N + gn] = v;
        else ((ushort*)Cv)[(size_t)gm * N + gn] = f2b(v);
      }
}

// ---------------- causal flash attention ----------------
// Q: [tok][16*128] bf16 (rope'd), K/V: [tok][4*128] bf16, O: [tok][16*128] bf16
// R7 structure: 256-row Q tiles, 512 threads = 8 waves, each wave owns 32 q rows
// with the EXACT R0 per-wave body (proven 128-VGPR allocation).
// Rationale from R5/R6 post-mortems:
//   - R0 cost = fixed per-iteration latency (staging + 2 barriers + shfl chains)
//     x iteration count. 256-row tiles: sum(4qt+4)=144 staged iters per (b,h)
//     vs 272 for 128-row tiles -> 1.9x fewer latency events, each hiding 2x MFMA.
//   - No LDS union, no third barrier (R6: union cost 20 VGPR + sync).
//   - Natural qt order (R6: permuting qt broke KV-group L2 lockstep, FETCH rose).
//   - LDS = 17.4K + 18.4K + Ps[256][72] 36.9K = 72.7K -> 2 blocks/CU = 16 waves/CU.
__global__ __launch_bounds__(512, 1) void attn_kernel(const ushort* __restrict__ Q,
                                                   const ushort* __restrict__ Kb,
                                                   const ushort* __restrict__ Vb,
                                                   ushort* __restrict__ O) {
  constexpr int T = 2048;
  __shared__ __align__(16) ushort Ks[64][136];   // K tile: 64 kv x 128 d (padded)
  __shared__ __align__(16) ushort Vts[128][72];  // V^T tile: 128 d x 64 kv (padded)
  __shared__ __align__(16) ushort Ps[256][72];   // P: 256 q x 64 kv (padded)

  const int qt = blockIdx.x, h = blockIdx.y, b = blockIdx.z;
  const int kvh = h >> 2;
  const int tid = threadIdx.x, wave = tid >> 6, lane = tid & 63;
  const int lr = lane & 15, lq = lane >> 4;
  const int q0 = qt * 256;
  const size_t qbase = (size_t)b * T * 2048 + (size_t)h * 128;
  const size_t kvbase = (size_t)b * T * 512 + (size_t)kvh * 128;

  // Q fragments in registers: wave rows [wave*32, wave*32+32)
  bf16x8 qf[2][4];
#pragma unroll
  for (int mi = 0; mi < 2; mi++)
#pragma unroll
    for (int kx = 0; kx < 4; kx++) {
      int row = q0 + wave * 32 + mi * 16 + lr;
      qf[mi][kx] = *(const bf16x8*)(Q + qbase + (size_t)row * 2048 + kx * 32 + lq * 8);
    }

  float mstate[2][4], lstate[2][4];
  f32x4 oacc[2][8] = {};
#pragma unroll
  for (int mi = 0; mi < 2; mi++)
#pragma unroll
    for (int r = 0; r < 4; r++) { mstate[mi][r] = -__builtin_inff(); lstate[mi][r] = 0.f; }

  const float SC = 0.08838834764831845f * 1.4426950408889634f; // 1/sqrt(128) * log2(e)
  const int jmax = 4 * qt + 3;

  const int krow = tid >> 4, kc = (tid & 15) * 8;     // K staging (512 thr: rows 0..31)
  const int vr = tid >> 3, vd0 = (tid & 7) * 2;       // V staging (transposed)

  for (int j = 0; j <= jmax; j++) {
    const int kv0 = j * 64;
    // stage K tile (coalesced): 2 passes x 32 rows
#pragma unroll
    for (int i = 0; i < 2; i++) {
      int r = krow + i * 32;
      uint4 v = *(const uint4*)(Kb + kvbase + (size_t)(kv0 + r) * 512 + kc);
      *(uint4*)(&Ks[r][kc]) = v;
    }
    // stage V transposed: each thread 8 uints
#pragma unroll
    for (int dd = 0; dd < 8; dd++) {
      int d = vd0 + dd * 16;
      uint v = *(const uint*)(Vb + kvbase + (size_t)(kv0 + vr) * 512 + d);
      Vts[d][vr] = (ushort)(v & 0xffffu);
      Vts[d + 1][vr] = (ushort)(v >> 16);
    }
    __syncthreads();

    // S = Q * K^T (32 x 64 per wave)
    f32x4 sacc[2][4] = {};
#pragma unroll
    for (int kx = 0; kx < 4; kx++) {
      bf16x8 kf[4];
#pragma unroll
      for (int ni = 0; ni < 4; ni++)
        kf[ni] = *(const bf16x8*)(&Ks[ni * 16 + lr][kx * 32 + lq * 8]);
#pragma unroll
      for (int mi = 0; mi < 2; mi++)
#pragma unroll
        for (int ni = 0; ni < 4; ni++)
          sacc[mi][ni] = __builtin_amdgcn_mfma_f32_16x16x32_bf16(qf[mi][kx], kf[ni], sacc[mi][ni], 0, 0, 0);
    }

    // online softmax per wave-owned rows (R0 body, mask always)
#pragma unroll
    for (int mi = 0; mi < 2; mi++) {
      float rmax[4];
#pragma unroll
      for (int r = 0; r < 4; r++) {
        int grow = q0 + wave * 32 + mi * 16 + lq * 4 + r;
        float mx = -__builtin_inff();
#pragma unroll
        for (int ni = 0; ni < 4; ni++) {
          float s = sacc[mi][ni][r] * SC;
          int gcol = kv0 + ni * 16 + lr;
          if (gcol > grow) s = -__builtin_inff();
          sacc[mi][ni][r] = s;
          mx = fmaxf(mx, s);
        }
        mx = fmaxf(mx, __shfl_xor(mx, 1));
        mx = fmaxf(mx, __shfl_xor(mx, 2));
        mx = fmaxf(mx, __shfl_xor(mx, 4));
        mx = fmaxf(mx, __shfl_xor(mx, 8));
        rmax[r] = mx;
      }
#pragma unroll
      for (int r = 0; r < 4; r++) {
        float mold = mstate[mi][r];
        float mnew = fmaxf(mold, rmax[r]);
        float alpha = exp2f(mold - mnew);
        float rs = 0.f;
#pragma unroll
        for (int ni = 0; ni < 4; ni++) {
          float p = exp2f(sacc[mi][ni][r] - mnew);
          sacc[mi][ni][r] = p;
          rs += p;
        }
        rs += __shfl_xor(rs, 1); rs += __shfl_xor(rs, 2);
        rs += __shfl_xor(rs, 4); rs += __shfl_xor(rs, 8);
        lstate[mi][r] = lstate[mi][r] * alpha + rs;
        mstate[mi][r] = mnew;
#pragma unroll
        for (int ni = 0; ni < 8; ni++) oacc[mi][ni][r] *= alpha;
      }
      // P -> LDS (C/D layout write); wave-private rows, read back by same wave
#pragma unroll
      for (int ni = 0; ni < 4; ni++)
#pragma unroll
        for (int r = 0; r < 4; r++)
          Ps[wave * 32 + mi * 16 + lq * 4 + r][ni * 16 + lr] = f2b(sacc[mi][ni][r]);
    }

    // O += P * V  (P: 32x64 A-layout from LDS, V^T for B operand)
#pragma unroll
    for (int k2 = 0; k2 < 2; k2++) {
      bf16x8 pf[2];
#pragma unroll
      for (int mi = 0; mi < 2; mi++)
        pf[mi] = *(const bf16x8*)(&Ps[wave * 32 + mi * 16 + lr][k2 * 32 + lq * 8]);
#pragma unroll
      for (int ni = 0; ni < 8; ni++) {
        bf16x8 vf = *(const bf16x8*)(&Vts[ni * 16 + lr][k2 * 32 + lq * 8]);
#pragma unroll
        for (int mi = 0; mi < 2; mi++)
          oacc[mi][ni] = __builtin_amdgcn_mfma_f32_16x16x32_bf16(pf[mi], vf, oacc[mi][ni], 0, 0, 0);
      }
    }
    __syncthreads();
  }

  // epilogue: O /= l, write bf16
#pragma unroll
  for (int mi = 0; mi < 2; mi++)
#pragma unroll
    for (int r = 0; r < 4; r++) {
      float inv = 1.0f / lstate[mi][r];
      int grow = q0 + wave * 32 + mi * 16 + lq * 4 + r;
      size_t base = ((size_t)b * T + grow) * 2048 + (size_t)h * 128;
#pragma unroll
      for (int ni = 0; ni < 8; ni++)
        O[base + ni * 16 + lr] = f2b(oacc[mi][ni][r] * inv);
    }
}

// ---------------- launcher ----------------
extern "C" void kernel_launch(void* const* d_in, const int* in_sizes, int n_in,
                              void* d_out, int out_size, void* d_ws, size_t ws_size,
                              hipStream_t stream) {
  const float* hs   = (const float*)d_in[0];
  const float* cosp = (const float*)d_in[1];
  const float* sinp = (const float*)d_in[2];
  const float* wq   = (const float*)d_in[3];
  const float* wk   = (const float*)d_in[4];
  const float* wv   = (const float*)d_in[5];
  const float* wo   = (const float*)d_in[6];
  float* out = (float*)d_out;

  char* p = (char*)d_ws;
  ushort* hs_b = (ushort*)p; p += (size_t)8192 * 2048 * 2;
  ushort* q_b  = (ushort*)p; p += (size_t)8192 * 2048 * 2;
  ushort* k_b  = (ushort*)p; p += (size_t)8192 * 512 * 2;
  ushort* v_b  = (ushort*)p; p += (size_t)8192 * 512 * 2;
  ushort* o_b  = (ushort*)p; p += (size_t)8192 * 2048 * 2;
  ushort* wq_b = (ushort*)p; p += (size_t)2048 * 2048 * 2;
  ushort* wk_b = (ushort*)p; p += (size_t)512 * 2048 * 2;
  ushort* wv_b = (ushort*)p; p += (size_t)512 * 2048 * 2;
  ushort* wo_b = (ushort*)p; p += (size_t)2048 * 2048 * 2;

  // conversions
  cvt_kernel<<<16384, 256, 0, stream>>>(hs, hs_b, 4194304);
  cvt_kernel<<<4096, 256, 0, stream>>>(wq, wq_b, 1048576);
  cvt_kernel<<<1024, 256, 0, stream>>>(wk, wk_b, 262144);
  cvt_kernel<<<1024, 256, 0, stream>>>(wv, wv_b, 262144);
  cvt_kernel<<<4096, 256, 0, stream>>>(wo, wo_b, 1048576);

  // projections
  gemm_nt<false><<<dim3(64, 16), 256, 0, stream>>>(hs_b, wq_b, q_b, 8192, 2048, 2048);
  gemm_nt<false><<<dim3(64, 4), 256, 0, stream>>>(hs_b, wk_b, k_b, 8192, 512, 2048);
  gemm_nt<false><<<dim3(64, 4), 256, 0, stream>>>(hs_b, wv_b, v_b, 8192, 512, 2048);

  // rope
  rope_kernel<<<32768, 256, 0, stream>>>(q_b, cosp, sinp, 16, 8388608);
  rope_kernel<<<8192, 256, 0, stream>>>(k_b, cosp, sinp, 4, 2097152);

  // attention: 256-row q tiles, 512 threads
  attn_kernel<<<dim3(8, 16, 4), 512, 0, stream>>>(q_b, k_b, v_b, o_b);

  // output projection (fp32 out)
  gemm_nt<true><<<dim3(64, 16), 256, 0, stream>>>(o_b, wo_b, out, 8192, 2048, 2048);
}

// Round 4
// 661.255 us; speedup vs baseline: 1.5909x; 1.1281x over previous
//
#include <hip/hip_runtime.h>

typedef __attribute__((ext_vector_type(8))) short bf16x8;
typedef __attribute__((ext_vector_type(4))) float f32x4;
typedef __attribute__((ext_vector_type(4))) ushort u16x4;

__device__ __forceinline__ ushort f2b(float x) {
  union { float f; uint u; } v; v.f = x;
  uint u = v.u;
  u += 0x7fffu + ((u >> 16) & 1u);
  return (ushort)(u >> 16);
}
__device__ __forceinline__ float b2f(ushort x) {
  union { uint u; float f; } v; v.u = ((uint)x) << 16;
  return v.f;
}

// async global->LDS, 16B per lane; lds base must be wave-uniform (HW scatters lane*16)
__device__ __forceinline__ void async16(const ushort* g, ushort* l) {
  __builtin_amdgcn_global_load_lds(
      (const __attribute__((address_space(1))) unsigned int*)g,
      (__attribute__((address_space(3))) unsigned int*)l, 16, 0, 0);
}

// ---------------- fp32 -> bf16 conversion ----------------
__global__ __launch_bounds__(256) void cvt_kernel(const float* __restrict__ in,
                                                  ushort* __restrict__ out, int n4) {
  int i = blockIdx.x * 256 + threadIdx.x;
  if (i >= n4) return;
  float4 v = ((const float4*)in)[i];
  ushort4 o;
  o.x = f2b(v.x); o.y = f2b(v.y); o.z = f2b(v.z); o.w = f2b(v.w);
  ((ushort4*)out)[i] = o;
}

// ---------------- RoPE (in-place on bf16), with output scale ----------------
// scale folds the softmax 1/sqrt(128)*log2(e) into Q (scale=1 for K).
__global__ __launch_bounds__(256) void rope_kernel(ushort* __restrict__ q,
                                                   const float* __restrict__ cs,
                                                   const float* __restrict__ sn,
                                                   int n_heads, int total, float scale) {
  int idx = blockIdx.x * 256 + threadIdx.x;
  if (idx >= total) return;
  int d = idx & 63;
  int h = (idx >> 6) % n_heads;
  int tok = idx / (64 * n_heads);
  ushort* p = q + (size_t)tok * (n_heads * 128) + h * 128 + d;
  float c = cs[(size_t)tok * 128 + d];
  float s = sn[(size_t)tok * 128 + d];
  float x1 = b2f(p[0]);
  float x2 = b2f(p[64]);
  p[0]  = f2b((x1 * c - x2 * s) * scale);
  p[64] = f2b((x2 * c + x1 * s) * scale);
}

// ---------------- NT GEMM: C[m,n] = sum_k A[m,k] * B[n,k] ----------------
// 128x128x64 tile, 4 waves (2x2 of 64x64). global_load_lds width-16 staging.
// R3 lesson: acc[4][4] must be fully unroll-indexed or it lives in scratch.
// R4 lesson: the LDS-DMA -> __syncthreads() edge needs an EXPLICIT
// s_waitcnt vmcnt(0); relying on the compiler's barrier drain raced
// intermittently under graph replay (post-timing absmax 0.248).
template <bool OUT_F32>
__global__ __launch_bounds__(256, 1) void gemm_nt(const ushort* __restrict__ A,
                                                  const ushort* __restrict__ B,
                                                  void* __restrict__ Cv,
                                                  int M, int N, int K) {
  __shared__ __align__(16) ushort As[128 * 64];
  __shared__ __align__(16) ushort Bs[128 * 64];
  const int tid = threadIdx.x;
  const int m0 = blockIdx.x * 128;
  const int n0 = blockIdx.y * 128;
  const int wave = tid >> 6, lane = tid & 63;
  const int wm = (wave >> 1) * 64, wn = (wave & 1) * 64;
  const int lr = lane & 15, lq = lane >> 4;

  // staging geometry: issue (i,wave) fills LDS chunk c16 = i*4+wave (8 rows x 64 cols);
  // lane -> row = c16*8 + (lane>>3), slot pos = lane&7, holds global chunk pos^(row&7)
  const int rsub = lane >> 3;     // 0..7
  const int pos = lane & 7;
  const int cg = pos ^ rsub;      // swizzled global 8-ushort chunk index

  // fragment LDS offsets (loop-invariant): read chunk c = ks*4+lq of row,
  // stored at position c ^ (row&7); row&7 == lr&7 here.
  int offA[4][2], offB[4][2];
#pragma unroll
  for (int mi = 0; mi < 4; mi++)
#pragma unroll
    for (int ks = 0; ks < 2; ks++) {
      int c = ks * 4 + lq;
      int sw = (c ^ (lr & 7)) * 8;
      offA[mi][ks] = (wm + mi * 16 + lr) * 64 + sw;
      offB[mi][ks] = (wn + mi * 16 + lr) * 64 + sw;
    }

  f32x4 acc[4][4] = {};

  for (int k0 = 0; k0 < K; k0 += 64) {
#pragma unroll
    for (int i = 0; i < 4; i++) {
      int c16 = i * 4 + wave;
      int row = c16 * 8 + rsub;
      async16(A + (size_t)(m0 + row) * K + k0 + cg * 8, &As[c16 * 512]);
      async16(B + (size_t)(n0 + row) * K + k0 + cg * 8, &Bs[c16 * 512]);
    }
    // explicit drain of the LDS-DMA before the barrier (see R4 note above)
    asm volatile("s_waitcnt vmcnt(0)" ::: "memory");
    __syncthreads();
#pragma unroll
    for (int ks = 0; ks < 2; ks++) {
      bf16x8 af[4], bfv[4];
#pragma unroll
      for (int mi = 0; mi < 4; mi++) af[mi] = *(const bf16x8*)(&As[offA[mi][ks]]);
#pragma unroll
      for (int ni = 0; ni < 4; ni++) bfv[ni] = *(const bf16x8*)(&Bs[offB[ni][ks]]);
#pragma unroll
      for (int mi = 0; mi < 4; mi++)
#pragma unroll
        for (int ni = 0; ni < 4; ni++)
          acc[mi][ni] = __builtin_amdgcn_mfma_f32_16x16x32_bf16(af[mi], bfv[ni], acc[mi][ni], 0, 0, 0);
    }
    __syncthreads();
  }

#pragma unroll
  for (int mi = 0; mi < 4; mi++)
#pragma unroll
    for (int ni = 0; ni < 4; ni++)
#pragma unroll
      for (int r = 0; r < 4; r++) {
        int gm = m0 + wm + mi * 16 + lq * 4 + r;
        int gn = n0 + wn + ni * 16 + lr;
        float v = acc[mi][ni][r];
        if (OUT_F32) ((float*)Cv)[(size_t)gm * N + gn] = v;
        else ((ushort*)Cv)[(size_t)gm * N + gn] = f2b(v);
      }
}

// ---------------- causal flash attention (swapped/transposed form) ----------------
// Q: [tok][16*128] bf16 (rope'd, PRE-SCALED by 1/sqrt(128)*log2e), K/V: [tok][4*128],
// O: [tok][16*128] bf16. 256-row Q tiles, 512 threads = 8 waves, wave owns 32 q rows.
// R4 theory: R0-R3 were LDS-instruction-bound (~160 DS ops/thread/iter: 64 shfl
// chains + 32 scalar b16 P-writes dominate; MfmaUtil+VALUBusy only ~33%).
// Swapped form: S^T = mfma(K, Q) uses the SAME Ks reads / qf registers with
// operand roles exchanged; C-layout then gives each lane 16 scores of ONE q-row
// (col = lr) -> row reduce = in-register + 2 shfl_xor (vs 4-deep chain x 8 rows).
// P^T written as 8 x b64 (vs 32 x b16). PV computed as O^T = mfma(V^T, P^T) --
// again identical Vts/Ps reads, swapped roles -- so alpha / 1/l stay lane-local
// and O stores become b64. Fully-masked (wave) tiles skip all compute
// (wave-uniform branch) to recover causal efficiency of the 256-row tile.
__global__ __launch_bounds__(512, 1) void attn_kernel(const ushort* __restrict__ Q,
                                                   const ushort* __restrict__ Kb,
                                                   const ushort* __restrict__ Vb,
                                                   ushort* __restrict__ O) {
  constexpr int T = 2048;
  __shared__ __align__(16) ushort Ks[64][136];   // K tile: 64 kv x 128 d (padded)
  __shared__ __align__(16) ushort Vts[128][72];  // V^T tile: 128 d x 64 kv (padded)
  __shared__ __align__(16) ushort Ps[256][72];   // P: 256 q x 64 kv (padded)

  const int qt = blockIdx.x, h = blockIdx.y, b = blockIdx.z;
  const int kvh = h >> 2;
  const int tid = threadIdx.x, wave = tid >> 6, lane = tid & 63;
  const int lr = lane & 15, lq = lane >> 4;
  const int q0 = qt * 256;
  const size_t qbase = (size_t)b * T * 2048 + (size_t)h * 128;
  const size_t kvbase = (size_t)b * T * 512 + (size_t)kvh * 128;

  // Q fragments (serve as B-operand of the swapped QK^T):
  // lane holds Q[q0+wave*32+mi*16+lr][kx*32+lq*8 .. +7]
  bf16x8 qf[2][4];
#pragma unroll
  for (int mi = 0; mi < 2; mi++)
#pragma unroll
    for (int kx = 0; kx < 4; kx++) {
      int row = q0 + wave * 32 + mi * 16 + lr;
      qf[mi][kx] = *(const bf16x8*)(Q + qbase + (size_t)row * 2048 + kx * 32 + lq * 8);
    }

  // oacc[mi][ni] holds O^T: d = ni*16 + lq*4 + r, q = mi*16 + lr (both + offsets)
  float mstate[2], lstate[2];
  f32x4 oacc[2][8] = {};
  mstate[0] = mstate[1] = -__builtin_inff();
  lstate[0] = lstate[1] = 0.f;

  const int jmax = 4 * qt + 3;
  const int qwmax = q0 + wave * 32 + 31;  // wave's last q row

  const int krow = tid >> 4, kc = (tid & 15) * 8;     // K staging (512 thr: rows 0..31)
  const int vr = tid >> 3, vd0 = (tid & 7) * 2;       // V staging (transposed)

  for (int j = 0; j <= jmax; j++) {
    const int kv0 = j * 64;
    // stage K tile (coalesced): 2 passes x 32 rows
#pragma unroll
    for (int i = 0; i < 2; i++) {
      int r = krow + i * 32;
      uint4 v = *(const uint4*)(Kb + kvbase + (size_t)(kv0 + r) * 512 + kc);
      *(uint4*)(&Ks[r][kc]) = v;
    }
    // stage V transposed: each thread 8 uints
#pragma unroll
    for (int dd = 0; dd < 8; dd++) {
      int d = vd0 + dd * 16;
      uint v = *(const uint*)(Vb + kvbase + (size_t)(kv0 + vr) * 512 + d);
      Vts[d][vr] = (ushort)(v & 0xffffu);
      Vts[d + 1][vr] = (ushort)(v >> 16);
    }
    __syncthreads();

    if (kv0 <= qwmax) {  // wave-uniform: skip fully-masked tiles
      // S^T = K * Q^T: scT[kt][mi], row kv = kt*16+lq*4+r, col q = mi*16+lr
      f32x4 scT[4][2] = {};
#pragma unroll
      for (int kx = 0; kx < 4; kx++) {
        bf16x8 kf[4];
#pragma unroll
        for (int kt = 0; kt < 4; kt++)
          kf[kt] = *(const bf16x8*)(&Ks[kt * 16 + lr][kx * 32 + lq * 8]);
#pragma unroll
        for (int kt = 0; kt < 4; kt++)
#pragma unroll
          for (int mi = 0; mi < 2; mi++)
            scT[kt][mi] = __builtin_amdgcn_mfma_f32_16x16x32_bf16(kf[kt], qf[mi][kx], scT[kt][mi], 0, 0, 0);
      }

#pragma unroll
      for (int mi = 0; mi < 2; mi++) {
        const int qrow = q0 + wave * 32 + mi * 16 + lr;
        float mx = -__builtin_inff();
        if (kv0 + 63 > q0 + wave * 32 + mi * 16) {  // partial tile: apply mask
#pragma unroll
          for (int kt = 0; kt < 4; kt++)
#pragma unroll
            for (int r = 0; r < 4; r++) {
              int kv = kv0 + kt * 16 + lq * 4 + r;
              float s = scT[kt][mi][r];
              if (kv > qrow) s = -__builtin_inff();
              scT[kt][mi][r] = s;
              mx = fmaxf(mx, s);
            }
        } else {
#pragma unroll
          for (int kt = 0; kt < 4; kt++)
#pragma unroll
            for (int r = 0; r < 4; r++) mx = fmaxf(mx, scT[kt][mi][r]);
        }
        mx = fmaxf(mx, __shfl_xor(mx, 16));
        mx = fmaxf(mx, __shfl_xor(mx, 32));
        float mold = mstate[mi];
        float mnew = fmaxf(mold, mx);
        float alpha = exp2f(mold - mnew);
        float rs = 0.f;
#pragma unroll
        for (int kt = 0; kt < 4; kt++)
#pragma unroll
          for (int r = 0; r < 4; r++) {
            float p = exp2f(scT[kt][mi][r] - mnew);
            scT[kt][mi][r] = p;
            rs += p;
          }
        rs += __shfl_xor(rs, 16);
        rs += __shfl_xor(rs, 32);
        lstate[mi] = lstate[mi] * alpha + rs;
        mstate[mi] = mnew;
#pragma unroll
        for (int ni = 0; ni < 8; ni++)
#pragma unroll
          for (int r = 0; r < 4; r++) oacc[mi][ni][r] *= alpha;
        // P^T -> LDS as Ps[q][kv], vectorized b64 (4 consecutive kv per lane)
#pragma unroll
        for (int kt = 0; kt < 4; kt++) {
          u16x4 w;
#pragma unroll
          for (int r = 0; r < 4; r++) w[r] = f2b(scT[kt][mi][r]);
          *(u16x4*)(&Ps[wave * 32 + mi * 16 + lr][kt * 16 + lq * 4]) = w;
        }
      }

      // O^T += V^T * P^T  (vf = A-operand from Vts, pf = B-operand from Ps;
      // identical reads as the unswapped form, roles exchanged)
#pragma unroll
      for (int k2 = 0; k2 < 2; k2++) {
        bf16x8 pf[2];
#pragma unroll
        for (int mi = 0; mi < 2; mi++)
          pf[mi] = *(const bf16x8*)(&Ps[wave * 32 + mi * 16 + lr][k2 * 32 + lq * 8]);
#pragma unroll
        for (int ni = 0; ni < 8; ni++) {
          bf16x8 vf = *(const bf16x8*)(&Vts[ni * 16 + lr][k2 * 32 + lq * 8]);
#pragma unroll
          for (int mi = 0; mi < 2; mi++)
            oacc[mi][ni] = __builtin_amdgcn_mfma_f32_16x16x32_bf16(vf, pf[mi], oacc[mi][ni], 0, 0, 0);
        }
      }
    }  // active
    __syncthreads();
  }

  // epilogue: O /= l; lane owns q = mi*16+lr, d = ni*16+lq*4..+3 -> b64 stores
#pragma unroll
  for (int mi = 0; mi < 2; mi++) {
    float inv = 1.0f / lstate[mi];
    int q = q0 + wave * 32 + mi * 16 + lr;
    size_t base = ((size_t)b * T + q) * 2048 + (size_t)h * 128;
#pragma unroll
    for (int ni = 0; ni < 8; ni++) {
      u16x4 w;
#pragma unroll
      for (int r = 0; r < 4; r++) w[r] = f2b(oacc[mi][ni][r] * inv);
      *(u16x4*)(&O[base + ni * 16 + lq * 4]) = w;
    }
  }
}

// ---------------- launcher ----------------
extern "C" void kernel_launch(void* const* d_in, const int* in_sizes, int n_in,
                              void* d_out, int out_size, void* d_ws, size_t ws_size,
                              hipStream_t stream) {
  const float* hs   = (const float*)d_in[0];
  const float* cosp = (const float*)d_in[1];
  const float* sinp = (const float*)d_in[2];
  const float* wq   = (const float*)d_in[3];
  const float* wk   = (const float*)d_in[4];
  const float* wv   = (const float*)d_in[5];
  const float* wo   = (const float*)d_in[6];
  float* out = (float*)d_out;

  char* p = (char*)d_ws;
  ushort* hs_b = (ushort*)p; p += (size_t)8192 * 2048 * 2;
  ushort* q_b  = (ushort*)p; p += (size_t)8192 * 2048 * 2;
  ushort* k_b  = (ushort*)p; p += (size_t)8192 * 512 * 2;
  ushort* v_b  = (ushort*)p; p += (size_t)8192 * 512 * 2;
  ushort* o_b  = (ushort*)p; p += (size_t)8192 * 2048 * 2;
  ushort* wq_b = (ushort*)p; p += (size_t)2048 * 2048 * 2;
  ushort* wk_b = (ushort*)p; p += (size_t)512 * 2048 * 2;
  ushort* wv_b = (ushort*)p; p += (size_t)512 * 2048 * 2;
  ushort* wo_b = (ushort*)p; p += (size_t)2048 * 2048 * 2;

  // conversions
  cvt_kernel<<<16384, 256, 0, stream>>>(hs, hs_b, 4194304);
  cvt_kernel<<<4096, 256, 0, stream>>>(wq, wq_b, 1048576);
  cvt_kernel<<<1024, 256, 0, stream>>>(wk, wk_b, 262144);
  cvt_kernel<<<1024, 256, 0, stream>>>(wv, wv_b, 262144);
  cvt_kernel<<<4096, 256, 0, stream>>>(wo, wo_b, 1048576);

  // projections
  gemm_nt<false><<<dim3(64, 16), 256, 0, stream>>>(hs_b, wq_b, q_b, 8192, 2048, 2048);
  gemm_nt<false><<<dim3(64, 4), 256, 0, stream>>>(hs_b, wk_b, k_b, 8192, 512, 2048);
  gemm_nt<false><<<dim3(64, 4), 256, 0, stream>>>(hs_b, wv_b, v_b, 8192, 512, 2048);

  // rope (Q gets the softmax scale folded in: 1/sqrt(128) * log2(e))
  const float SC = 0.08838834764831845f * 1.4426950408889634f;
  rope_kernel<<<32768, 256, 0, stream>>>(q_b, cosp, sinp, 16, 8388608, SC);
  rope_kernel<<<8192, 256, 0, stream>>>(k_b, cosp, sinp, 4, 2097152, 1.0f);

  // attention: 256-row q tiles, 512 threads
  attn_kernel<<<dim3(8, 16, 4), 512, 0, stream>>>(q_b, k_b, v_b, o_b);

  // output projection (fp32 out)
  gemm_nt<true><<<dim3(64, 16), 256, 0, stream>>>(o_b, wo_b, out, 8192, 2048, 2048);
}

// Round 5
// 659.918 us; speedup vs baseline: 1.5941x; 1.0020x over previous
//
#include <hip/hip_runtime.h>

typedef __attribute__((ext_vector_type(8))) short bf16x8;
typedef __attribute__((ext_vector_type(4))) float f32x4;
typedef __attribute__((ext_vector_type(4))) ushort u16x4;

__device__ __forceinline__ ushort f2b(float x) {
  union { float f; uint u; } v; v.f = x;
  uint u = v.u;
  u += 0x7fffu + ((u >> 16) & 1u);
  return (ushort)(u >> 16);
}
__device__ __forceinline__ float b2f(ushort x) {
  union { uint u; float f; } v; v.u = ((uint)x) << 16;
  return v.f;
}

// async global->LDS, 16B per lane; lds base must be wave-uniform (HW scatters lane*16)
__device__ __forceinline__ void async16(const ushort* g, ushort* l) {
  __builtin_amdgcn_global_load_lds(
      (const __attribute__((address_space(1))) unsigned int*)g,
      (__attribute__((address_space(3))) unsigned int*)l, 16, 0, 0);
}

// ---------------- fp32 -> bf16 conversion ----------------
__global__ __launch_bounds__(256) void cvt_kernel(const float* __restrict__ in,
                                                  ushort* __restrict__ out, int n4) {
  int i = blockIdx.x * 256 + threadIdx.x;
  if (i >= n4) return;
  float4 v = ((const float4*)in)[i];
  ushort4 o;
  o.x = f2b(v.x); o.y = f2b(v.y); o.z = f2b(v.z); o.w = f2b(v.w);
  ((ushort4*)out)[i] = o;
}

// ---------------- RoPE (in-place on bf16), with output scale ----------------
// scale folds the softmax 1/sqrt(128)*log2(e) into Q (scale=1 for K).
__global__ __launch_bounds__(256) void rope_kernel(ushort* __restrict__ q,
                                                   const float* __restrict__ cs,
                                                   const float* __restrict__ sn,
                                                   int n_heads, int total, float scale) {
  int idx = blockIdx.x * 256 + threadIdx.x;
  if (idx >= total) return;
  int d = idx & 63;
  int h = (idx >> 6) % n_heads;
  int tok = idx / (64 * n_heads);
  ushort* p = q + (size_t)tok * (n_heads * 128) + h * 128 + d;
  float c = cs[(size_t)tok * 128 + d];
  float s = sn[(size_t)tok * 128 + d];
  float x1 = b2f(p[0]);
  float x2 = b2f(p[64]);
  p[0]  = f2b((x1 * c - x2 * s) * scale);
  p[64] = f2b((x2 * c + x1 * s) * scale);
}

// ---------------- NT GEMM: C[m,n] = sum_k A[m,k] * B[n,k] ----------------
// 128x128x64 tile, 4 waves (2x2 of 64x64). global_load_lds width-16 staging.
// R3 lesson: acc[4][4] must be fully unroll-indexed or it lives in scratch.
// R4 lesson: the LDS-DMA -> __syncthreads() edge needs an EXPLICIT
// s_waitcnt vmcnt(0); relying on the compiler's barrier drain raced
// intermittently under graph replay (post-timing absmax 0.248).
template <bool OUT_F32>
__global__ __launch_bounds__(256, 1) void gemm_nt(const ushort* __restrict__ A,
                                                  const ushort* __restrict__ B,
                                                  void* __restrict__ Cv,
                                                  int M, int N, int K) {
  __shared__ __align__(16) ushort As[128 * 64];
  __shared__ __align__(16) ushort Bs[128 * 64];
  const int tid = threadIdx.x;
  const int m0 = blockIdx.x * 128;
  const int n0 = blockIdx.y * 128;
  const int wave = tid >> 6, lane = tid & 63;
  const int wm = (wave >> 1) * 64, wn = (wave & 1) * 64;
  const int lr = lane & 15, lq = lane >> 4;

  // staging geometry: issue (i,wave) fills LDS chunk c16 = i*4+wave (8 rows x 64 cols);
  // lane -> row = c16*8 + (lane>>3), slot pos = lane&7, holds global chunk pos^(row&7)
  const int rsub = lane >> 3;     // 0..7
  const int pos = lane & 7;
  const int cg = pos ^ rsub;      // swizzled global 8-ushort chunk index

  // fragment LDS offsets (loop-invariant): read chunk c = ks*4+lq of row,
  // stored at position c ^ (row&7); row&7 == lr&7 here.
  int offA[4][2], offB[4][2];
#pragma unroll
  for (int mi = 0; mi < 4; mi++)
#pragma unroll
    for (int ks = 0; ks < 2; ks++) {
      int c = ks * 4 + lq;
      int sw = (c ^ (lr & 7)) * 8;
      offA[mi][ks] = (wm + mi * 16 + lr) * 64 + sw;
      offB[mi][ks] = (wn + mi * 16 + lr) * 64 + sw;
    }

  f32x4 acc[4][4] = {};

  for (int k0 = 0; k0 < K; k0 += 64) {
#pragma unroll
    for (int i = 0; i < 4; i++) {
      int c16 = i * 4 + wave;
      int row = c16 * 8 + rsub;
      async16(A + (size_t)(m0 + row) * K + k0 + cg * 8, &As[c16 * 512]);
      async16(B + (size_t)(n0 + row) * K + k0 + cg * 8, &Bs[c16 * 512]);
    }
    // explicit drain of the LDS-DMA before the barrier (see R4 note above)
    asm volatile("s_waitcnt vmcnt(0)" ::: "memory");
    __syncthreads();
#pragma unroll
    for (int ks = 0; ks < 2; ks++) {
      bf16x8 af[4], bfv[4];
#pragma unroll
      for (int mi = 0; mi < 4; mi++) af[mi] = *(const bf16x8*)(&As[offA[mi][ks]]);
#pragma unroll
      for (int ni = 0; ni < 4; ni++) bfv[ni] = *(const bf16x8*)(&Bs[offB[ni][ks]]);
#pragma unroll
      for (int mi = 0; mi < 4; mi++)
#pragma unroll
        for (int ni = 0; ni < 4; ni++)
          acc[mi][ni] = __builtin_amdgcn_mfma_f32_16x16x32_bf16(af[mi], bfv[ni], acc[mi][ni], 0, 0, 0);
    }
    __syncthreads();
  }

#pragma unroll
  for (int mi = 0; mi < 4; mi++)
#pragma unroll
    for (int ni = 0; ni < 4; ni++)
#pragma unroll
      for (int r = 0; r < 4; r++) {
        int gm = m0 + wm + mi * 16 + lq * 4 + r;
        int gn = n0 + wn + ni * 16 + lr;
        float v = acc[mi][ni][r];
        if (OUT_F32) ((float*)Cv)[(size_t)gm * N + gn] = v;
        else ((ushort*)Cv)[(size_t)gm * N + gn] = f2b(v);
      }
}

// ---------------- causal flash attention (swapped/transposed form) ----------------
// Q: [tok][16*128] bf16 (rope'd, PRE-SCALED by 1/sqrt(128)*log2e), K/V: [tok][4*128],
// O: [tok][16*128] bf16. 256-row Q tiles, 512 threads = 8 waves, wave owns 32 q rows.
// R4: swapped QK^T / PV keep softmax lane-local (attn 361 -> 260 us).
// R5: XCD LOAD BALANCE. grid=(8,16,4) with blockIdx.x=qt meant linear%8 == qt,
// so XCD 7 got ALL 64 qt=7 blocks (32 iters each) while XCD 0 idled after its
// qt=0 blocks (4 iters): per-XCD work 64*(4x+4), a 1.8x built-in tail. This is
// why R3's iteration-halving didn't move dur. Fix: derive qt from a remap
//   s = (x+h)&7;  qt = (b&2) ? 7-s : s
// - XCD level (linear%8 == x): for fixed x, qt covers each value uniformly over
//   (h,b) -> every XCD gets identical work by construction.
// - CU level: likely co-resident pair (same x,h; b and b+2) gets complementary
//   qt (s, 7-s) -> constant 36 block-iters per CU pair (best-effort, relies on
//   arrival-order guess; harmless if wrong).
// K/V locality is a non-issue: total K/V = 16.8 MB, L3-resident (FETCH 53 MB).
__global__ __launch_bounds__(512, 1) void attn_kernel(const ushort* __restrict__ Q,
                                                   const ushort* __restrict__ Kb,
                                                   const ushort* __restrict__ Vb,
                                                   ushort* __restrict__ O) {
  constexpr int T = 2048;
  __shared__ __align__(16) ushort Ks[64][136];   // K tile: 64 kv x 128 d (padded)
  __shared__ __align__(16) ushort Vts[128][72];  // V^T tile: 128 d x 64 kv (padded)
  __shared__ __align__(16) ushort Ps[256][72];   // P: 256 q x 64 kv (padded)

  const int h = blockIdx.y, b = blockIdx.z;
  const int s = (blockIdx.x + h) & 7;
  const int qt = (b & 2) ? (7 - s) : s;   // XCD/CU load-balance remap (see header)
  const int kvh = h >> 2;
  const int tid = threadIdx.x, wave = tid >> 6, lane = tid & 63;
  const int lr = lane & 15, lq = lane >> 4;
  const int q0 = qt * 256;
  const size_t qbase = (size_t)b * T * 2048 + (size_t)h * 128;
  const size_t kvbase = (size_t)b * T * 512 + (size_t)kvh * 128;

  // Q fragments (serve as B-operand of the swapped QK^T):
  // lane holds Q[q0+wave*32+mi*16+lr][kx*32+lq*8 .. +7]
  bf16x8 qf[2][4];
#pragma unroll
  for (int mi = 0; mi < 2; mi++)
#pragma unroll
    for (int kx = 0; kx < 4; kx++) {
      int row = q0 + wave * 32 + mi * 16 + lr;
      qf[mi][kx] = *(const bf16x8*)(Q + qbase + (size_t)row * 2048 + kx * 32 + lq * 8);
    }

  // oacc[mi][ni] holds O^T: d = ni*16 + lq*4 + r, q = mi*16 + lr (both + offsets)
  float mstate[2], lstate[2];
  f32x4 oacc[2][8] = {};
  mstate[0] = mstate[1] = -__builtin_inff();
  lstate[0] = lstate[1] = 0.f;

  const int jmax = 4 * qt + 3;
  const int qwmax = q0 + wave * 32 + 31;  // wave's last q row

  const int krow = tid >> 4, kc = (tid & 15) * 8;     // K staging (512 thr: rows 0..31)
  const int vr = tid >> 3, vd0 = (tid & 7) * 2;       // V staging (transposed)

  for (int j = 0; j <= jmax; j++) {
    const int kv0 = j * 64;
    // stage K tile (coalesced): 2 passes x 32 rows
#pragma unroll
    for (int i = 0; i < 2; i++) {
      int r = krow + i * 32;
      uint4 v = *(const uint4*)(Kb + kvbase + (size_t)(kv0 + r) * 512 + kc);
      *(uint4*)(&Ks[r][kc]) = v;
    }
    // stage V transposed: each thread 8 uints
#pragma unroll
    for (int dd = 0; dd < 8; dd++) {
      int d = vd0 + dd * 16;
      uint v = *(const uint*)(Vb + kvbase + (size_t)(kv0 + vr) * 512 + d);
      Vts[d][vr] = (ushort)(v & 0xffffu);
      Vts[d + 1][vr] = (ushort)(v >> 16);
    }
    __syncthreads();

    if (kv0 <= qwmax) {  // wave-uniform: skip fully-masked tiles
      // S^T = K * Q^T: scT[kt][mi], row kv = kt*16+lq*4+r, col q = mi*16+lr
      f32x4 scT[4][2] = {};
#pragma unroll
      for (int kx = 0; kx < 4; kx++) {
        bf16x8 kf[4];
#pragma unroll
        for (int kt = 0; kt < 4; kt++)
          kf[kt] = *(const bf16x8*)(&Ks[kt * 16 + lr][kx * 32 + lq * 8]);
#pragma unroll
        for (int kt = 0; kt < 4; kt++)
#pragma unroll
          for (int mi = 0; mi < 2; mi++)
            scT[kt][mi] = __builtin_amdgcn_mfma_f32_16x16x32_bf16(kf[kt], qf[mi][kx], scT[kt][mi], 0, 0, 0);
      }

#pragma unroll
      for (int mi = 0; mi < 2; mi++) {
        const int qrow = q0 + wave * 32 + mi * 16 + lr;
        float mx = -__builtin_inff();
        if (kv0 + 63 > q0 + wave * 32 + mi * 16) {  // partial tile: apply mask
#pragma unroll
          for (int kt = 0; kt < 4; kt++)
#pragma unroll
            for (int r = 0; r < 4; r++) {
              int kv = kv0 + kt * 16 + lq * 4 + r;
              float s2 = scT[kt][mi][r];
              if (kv > qrow) s2 = -__builtin_inff();
              scT[kt][mi][r] = s2;
              mx = fmaxf(mx, s2);
            }
        } else {
#pragma unroll
          for (int kt = 0; kt < 4; kt++)
#pragma unroll
            for (int r = 0; r < 4; r++) mx = fmaxf(mx, scT[kt][mi][r]);
        }
        mx = fmaxf(mx, __shfl_xor(mx, 16));
        mx = fmaxf(mx, __shfl_xor(mx, 32));
        float mold = mstate[mi];
        float mnew = fmaxf(mold, mx);
        float alpha = exp2f(mold - mnew);
        float rs = 0.f;
#pragma unroll
        for (int kt = 0; kt < 4; kt++)
#pragma unroll
          for (int r = 0; r < 4; r++) {
            float p = exp2f(scT[kt][mi][r] - mnew);
            scT[kt][mi][r] = p;
            rs += p;
          }
        rs += __shfl_xor(rs, 16);
        rs += __shfl_xor(rs, 32);
        lstate[mi] = lstate[mi] * alpha + rs;
        mstate[mi] = mnew;
#pragma unroll
        for (int ni = 0; ni < 8; ni++)
#pragma unroll
          for (int r = 0; r < 4; r++) oacc[mi][ni][r] *= alpha;
        // P^T -> LDS as Ps[q][kv], vectorized b64 (4 consecutive kv per lane)
#pragma unroll
        for (int kt = 0; kt < 4; kt++) {
          u16x4 w;
#pragma unroll
          for (int r = 0; r < 4; r++) w[r] = f2b(scT[kt][mi][r]);
          *(u16x4*)(&Ps[wave * 32 + mi * 16 + lr][kt * 16 + lq * 4]) = w;
        }
      }

      // O^T += V^T * P^T  (vf = A-operand from Vts, pf = B-operand from Ps;
      // identical reads as the unswapped form, roles exchanged)
#pragma unroll
      for (int k2 = 0; k2 < 2; k2++) {
        bf16x8 pf[2];
#pragma unroll
        for (int mi = 0; mi < 2; mi++)
          pf[mi] = *(const bf16x8*)(&Ps[wave * 32 + mi * 16 + lr][k2 * 32 + lq * 8]);
#pragma unroll
        for (int ni = 0; ni < 8; ni++) {
          bf16x8 vf = *(const bf16x8*)(&Vts[ni * 16 + lr][k2 * 32 + lq * 8]);
#pragma unroll
          for (int mi = 0; mi < 2; mi++)
            oacc[mi][ni] = __builtin_amdgcn_mfma_f32_16x16x32_bf16(vf, pf[mi], oacc[mi][ni], 0, 0, 0);
        }
      }
    }  // active
    __syncthreads();
  }

  // epilogue: O /= l; lane owns q = mi*16+lr, d = ni*16+lq*4..+3 -> b64 stores
#pragma unroll
  for (int mi = 0; mi < 2; mi++) {
    float inv = 1.0f / lstate[mi];
    int q = q0 + wave * 32 + mi * 16 + lr;
    size_t base = ((size_t)b * T + q) * 2048 + (size_t)h * 128;
#pragma unroll
    for (int ni = 0; ni < 8; ni++) {
      u16x4 w;
#pragma unroll
      for (int r = 0; r < 4; r++) w[r] = f2b(oacc[mi][ni][r] * inv);
      *(u16x4*)(&O[base + ni * 16 + lq * 4]) = w;
    }
  }
}

// ---------------- launcher ----------------
extern "C" void kernel_launch(void* const* d_in, const int* in_sizes, int n_in,
                              void* d_out, int out_size, void* d_ws, size_t ws_size,
                              hipStream_t stream) {
  const float* hs   = (const float*)d_in[0];
  const float* cosp = (const float*)d_in[1];
  const float* sinp = (const float*)d_in[2];
  const float* wq   = (const float*)d_in[3];
  const float* wk   = (const float*)d_in[4];
  const float* wv   = (const float*)d_in[5];
  const float* wo   = (const float*)d_in[6];
  float* out = (float*)d_out;

  char* p = (char*)d_ws;
  ushort* hs_b = (ushort*)p; p += (size_t)8192 * 2048 * 2;
  ushort* q_b  = (ushort*)p; p += (size_t)8192 * 2048 * 2;
  ushort* k_b  = (ushort*)p; p += (size_t)8192 * 512 * 2;
  ushort* v_b  = (ushort*)p; p += (size_t)8192 * 512 * 2;
  ushort* o_b  = (ushort*)p; p += (size_t)8192 * 2048 * 2;
  ushort* wq_b = (ushort*)p; p += (size_t)2048 * 2048 * 2;
  ushort* wk_b = (ushort*)p; p += (size_t)512 * 2048 * 2;
  ushort* wv_b = (ushort*)p; p += (size_t)512 * 2048 * 2;
  ushort* wo_b = (ushort*)p; p += (size_t)2048 * 2048 * 2;

  // conversions
  cvt_kernel<<<16384, 256, 0, stream>>>(hs, hs_b, 4194304);
  cvt_kernel<<<4096, 256, 0, stream>>>(wq, wq_b, 1048576);
  cvt_kernel<<<1024, 256, 0, stream>>>(wk, wk_b, 262144);
  cvt_kernel<<<1024, 256, 0, stream>>>(wv, wv_b, 262144);
  cvt_kernel<<<4096, 256, 0, stream>>>(wo, wo_b, 1048576);

  // projections
  gemm_nt<false><<<dim3(64, 16), 256, 0, stream>>>(hs_b, wq_b, q_b, 8192, 2048, 2048);
  gemm_nt<false><<<dim3(64, 4), 256, 0, stream>>>(hs_b, wk_b, k_b, 8192, 512, 2048);
  gemm_nt<false><<<dim3(64, 4), 256, 0, stream>>>(hs_b, wv_b, v_b, 8192, 512, 2048);

  // rope (Q gets the softmax scale folded in: 1/sqrt(128) * log2(e))
  const float SC = 0.08838834764831845f * 1.4426950408889634f;
  rope_kernel<<<32768, 256, 0, stream>>>(q_b, cosp, sinp, 16, 8388608, SC);
  rope_kernel<<<8192, 256, 0, stream>>>(k_b, cosp, sinp, 4, 2097152, 1.0f);

  // attention: 256-row q tiles, 512 threads, load-balanced qt remap
  attn_kernel<<<dim3(8, 16, 4), 512, 0, stream>>>(q_b, k_b, v_b, o_b);

  // output projection (fp32 out)
  gemm_nt<true><<<dim3(64, 16), 256, 0, stream>>>(o_b, wo_b, out, 8192, 2048, 2048);
}

// Round 7
// 642.767 us; speedup vs baseline: 1.6366x; 1.0267x over previous
//
#include <hip/hip_runtime.h>

typedef __attribute__((ext_vector_type(8))) short bf16x8;
typedef __attribute__((ext_vector_type(4))) float f32x4;
typedef __attribute__((ext_vector_type(4))) ushort u16x4;

__device__ __forceinline__ ushort f2b(float x) {
  union { float f; uint u; } v; v.f = x;
  uint u = v.u;
  u += 0x7fffu + ((u >> 16) & 1u);
  return (ushort)(u >> 16);
}
__device__ __forceinline__ float b2f(ushort x) {
  union { uint u; float f; } v; v.u = ((uint)x) << 16;
  return v.f;
}

// async global->LDS, 16B per lane; lds base must be wave-uniform (HW scatters lane*16)
__device__ __forceinline__ void async16(const ushort* g, ushort* l) {
  __builtin_amdgcn_global_load_lds(
      (const __attribute__((address_space(1))) unsigned int*)g,
      (__attribute__((address_space(3))) unsigned int*)l, 16, 0, 0);
}

// ---------------- fp32 -> bf16 conversion ----------------
__global__ __launch_bounds__(256) void cvt_kernel(const float* __restrict__ in,
                                                  ushort* __restrict__ out, int n4) {
  int i = blockIdx.x * 256 + threadIdx.x;
  if (i >= n4) return;
  float4 v = ((const float4*)in)[i];
  ushort4 o;
  o.x = f2b(v.x); o.y = f2b(v.y); o.z = f2b(v.z); o.w = f2b(v.w);
  ((ushort4*)out)[i] = o;
}

// ---------------- RoPE (in-place on bf16), with output scale ----------------
__global__ __launch_bounds__(256) void rope_kernel(ushort* __restrict__ q,
                                                   const float* __restrict__ cs,
                                                   const float* __restrict__ sn,
                                                   int n_heads, int total, float scale) {
  int idx = blockIdx.x * 256 + threadIdx.x;
  if (idx >= total) return;
  int d = idx & 63;
  int h = (idx >> 6) % n_heads;
  int tok = idx / (64 * n_heads);
  ushort* p = q + (size_t)tok * (n_heads * 128) + h * 128 + d;
  float c = cs[(size_t)tok * 128 + d];
  float s = sn[(size_t)tok * 128 + d];
  float x1 = b2f(p[0]);
  float x2 = b2f(p[64]);
  p[0]  = f2b((x1 * c - x2 * s) * scale);
  p[64] = f2b((x2 * c + x1 * s) * scale);
}

// ---------------- NT GEMM: C[m,n] = sum_k A[m,k] * B[n,k] ----------------
// 128x128x64 tile, 4 waves (2x2 of 64x64). global_load_lds width-16 staging.
template <bool OUT_F32>
__global__ __launch_bounds__(256, 1) void gemm_nt(const ushort* __restrict__ A,
                                                  const ushort* __restrict__ B,
                                                  void* __restrict__ Cv,
                                                  int M, int N, int K) {
  __shared__ __align__(16) ushort As[128 * 64];
  __shared__ __align__(16) ushort Bs[128 * 64];
  const int tid = threadIdx.x;
  const int m0 = blockIdx.x * 128;
  const int n0 = blockIdx.y * 128;
  const int wave = tid >> 6, lane = tid & 63;
  const int wm = (wave >> 1) * 64, wn = (wave & 1) * 64;
  const int lr = lane & 15, lq = lane >> 4;

  const int rsub = lane >> 3;     // 0..7
  const int pos = lane & 7;
  const int cg = pos ^ rsub;      // swizzled global 8-ushort chunk index

  int offA[4][2], offB[4][2];
#pragma unroll
  for (int mi = 0; mi < 4; mi++)
#pragma unroll
    for (int ks = 0; ks < 2; ks++) {
      int c = ks * 4 + lq;
      int sw = (c ^ (lr & 7)) * 8;
      offA[mi][ks] = (wm + mi * 16 + lr) * 64 + sw;
      offB[mi][ks] = (wn + mi * 16 + lr) * 64 + sw;
    }

  f32x4 acc[4][4] = {};

  for (int k0 = 0; k0 < K; k0 += 64) {
#pragma unroll
    for (int i = 0; i < 4; i++) {
      int c16 = i * 4 + wave;
      int row = c16 * 8 + rsub;
      async16(A + (size_t)(m0 + row) * K + k0 + cg * 8, &As[c16 * 512]);
      async16(B + (size_t)(n0 + row) * K + k0 + cg * 8, &Bs[c16 * 512]);
    }
    // explicit drain of the LDS-DMA before the barrier (R4 lesson: races without)
    asm volatile("s_waitcnt vmcnt(0)" ::: "memory");
    __syncthreads();
#pragma unroll
    for (int ks = 0; ks < 2; ks++) {
      bf16x8 af[4], bfv[4];
#pragma unroll
      for (int mi = 0; mi < 4; mi++) af[mi] = *(const bf16x8*)(&As[offA[mi][ks]]);
#pragma unroll
      for (int ni = 0; ni < 4; ni++) bfv[ni] = *(const bf16x8*)(&Bs[offB[ni][ks]]);
#pragma unroll
      for (int mi = 0; mi < 4; mi++)
#pragma unroll
        for (int ni = 0; ni < 4; ni++)
          acc[mi][ni] = __builtin_amdgcn_mfma_f32_16x16x32_bf16(af[mi], bfv[ni], acc[mi][ni], 0, 0, 0);
    }
    __syncthreads();
  }

#pragma unroll
  for (int mi = 0; mi < 4; mi++)
#pragma unroll
    for (int ni = 0; ni < 4; ni++)
#pragma unroll
      for (int r = 0; r < 4; r++) {
        int gm = m0 + wm + mi * 16 + lq * 4 + r;
        int gn = n0 + wn + ni * 16 + lr;
        float v = acc[mi][ni][r];
        if (OUT_F32) ((float*)Cv)[(size_t)gm * N + gn] = v;
        else ((ushort*)Cv)[(size_t)gm * N + gn] = f2b(v);
      }
}

// ---------------- causal flash attention (swapped form, R7) ----------------
// R4: swapped QK^T / PV keep softmax lane-local (361 -> 260 us).
// R5: XCD qt remap (260 -> 245 us).
// R6 FAILED (NaN) -- root cause identified: the m/l reductions used
//   uint x = bit(mx), y = x;  asm(permlane32_swap : "+v"(x), "+v"(y));
// x,y provably equal -> register allocator coalesced them -> swap vN,vN ->
// no exchange -> per-lane partial max -> -inf on fully-masked diagonal lanes
// -> exp2f(-inf - -inf) = NaN. R7 reverts ONLY the reductions to proven
// __shfl_xor(.,16/32); keeps the three R6 mechanisms:
//   (a) Ps ELIMINATED: P^T redistributed in-register via cvt_pk + permlane
//       swaps (s0..s3 are distinct values -> no coalescing hazard).
//       Dest word (g=lq, k2, w) needs S[2k2+(g>>1)][w&1] from lane
//       lq_src = 2(g&1)+(w>>1); the swap32/swap16 network delivers exactly
//       that (element-wise verified, see derivation in session journal).
//   (b) K/V double-buffered: loads for j+2 issued before compute of j;
//       ONE barrier per iter; writes of tile j+1 go to buf cur^1 while
//       compute reads buf cur (reads of cur^1 are barrier-separated).
//   (c) V-transpose write bank swizzle: col = kr ^ ((d&0x70)>>1). Old
//       pattern was 16-way conflict x 16 writes/thread/iter ~= the entire
//       1.4e7 SQ_LDS_BANK_CONFLICT. Reads use col ^ (ni<<3).
__global__ __launch_bounds__(512, 1) void attn_kernel(const ushort* __restrict__ Q,
                                                   const ushort* __restrict__ Kb,
                                                   const ushort* __restrict__ Vb,
                                                   ushort* __restrict__ O) {
  constexpr int T = 2048;
  __shared__ __align__(16) ushort Ks[2][64][136];   // K tiles (double-buffered)
  __shared__ __align__(16) ushort Vts[2][128][72];  // V^T tiles (swizzled cols)

  const int h = blockIdx.y, b = blockIdx.z;
  const int s = (blockIdx.x + h) & 7;
  const int qt = (b & 2) ? (7 - s) : s;   // R5 XCD balance remap
  const int kvh = h >> 2;
  const int tid = threadIdx.x, wave = tid >> 6, lane = tid & 63;
  const int lr = lane & 15, lq = lane >> 4;
  const int q0 = qt * 256;
  const size_t qbase = (size_t)b * T * 2048 + (size_t)h * 128;
  const size_t kvbase = (size_t)b * T * 512 + (size_t)kvh * 128;

  // Q fragments (B-operand of swapped QK^T): lane holds Q[row=..+lr][kx*32+lq*8..+7]
  bf16x8 qf[2][4];
#pragma unroll
  for (int mi = 0; mi < 2; mi++)
#pragma unroll
    for (int kx = 0; kx < 4; kx++) {
      int row = q0 + wave * 32 + mi * 16 + lr;
      qf[mi][kx] = *(const bf16x8*)(Q + qbase + (size_t)row * 2048 + kx * 32 + lq * 8);
    }

  float mstate[2], lstate[2];
  f32x4 oacc[2][8] = {};
  mstate[0] = mstate[1] = -__builtin_inff();
  lstate[0] = lstate[1] = 0.f;

  const int jmax = 4 * qt + 3;
  const int qwmax = q0 + wave * 32 + 31;

  // staging: thread owns K/V row kr, 16 consecutive ushorts at kc16 (2x uint4, coalesced)
  const int kr = tid >> 3;
  const int kc16 = (tid & 7) * 16;

  uint4 ka, kb2, va, vb2;
  auto loadkv = [&](int j) {
    const ushort* kp = Kb + kvbase + (size_t)(j * 64 + kr) * 512 + kc16;
    ka  = *(const uint4*)kp;
    kb2 = *(const uint4*)(kp + 8);
    const ushort* vp = Vb + kvbase + (size_t)(j * 64 + kr) * 512 + kc16;
    va  = *(const uint4*)vp;
    vb2 = *(const uint4*)(vp + 8);
  };
  auto writekv = [&](int bf) {
    *(uint4*)(&Ks[bf][kr][kc16])     = ka;
    *(uint4*)(&Ks[bf][kr][kc16 + 8]) = kb2;
    uint w[8] = {va.x, va.y, va.z, va.w, vb2.x, vb2.y, vb2.z, vb2.w};
#pragma unroll
    for (int i = 0; i < 8; i++) {
      int d0 = kc16 + 2 * i;
      int c0 = kr ^ ((d0 & 0x70) >> 1);       // bank swizzle (same for d0, d0+1)
      Vts[bf][d0][c0]     = (ushort)(w[i] & 0xffffu);
      Vts[bf][d0 + 1][c0] = (ushort)(w[i] >> 16);
    }
  };

  loadkv(0);
  writekv(0);
  loadkv(1);
  __syncthreads();

  for (int j = 0; j <= jmax; ++j) {
    const int cur = j & 1;
    if (j < jmax) writekv(cur ^ 1);      // stage tile j+1 (regs loaded last iter)
    if (j + 1 < jmax) loadkv(j + 2);     // issue tile j+2 loads; hide under compute
    const int kv0 = j * 64;

    if (kv0 <= qwmax) {  // wave-uniform skip of fully-masked tiles
      // S^T = K * Q^T: scT[kt][mi], kv = kt*16+lq*4+r, q = mi*16+lr
      f32x4 scT[4][2] = {};
#pragma unroll
      for (int kx = 0; kx < 4; kx++) {
        bf16x8 kf[4];
#pragma unroll
        for (int kt = 0; kt < 4; kt++)
          kf[kt] = *(const bf16x8*)(&Ks[cur][kt * 16 + lr][kx * 32 + lq * 8]);
#pragma unroll
        for (int kt = 0; kt < 4; kt++)
#pragma unroll
          for (int mi = 0; mi < 2; mi++)
            scT[kt][mi] = __builtin_amdgcn_mfma_f32_16x16x32_bf16(kf[kt], qf[mi][kx], scT[kt][mi], 0, 0, 0);
      }

      bf16x8 pf[2][2];
#pragma unroll
      for (int mi = 0; mi < 2; mi++) {
        const int qrow = q0 + wave * 32 + mi * 16 + lr;
        float mx = -__builtin_inff();
        if (kv0 + 63 > q0 + wave * 32 + mi * 16) {  // diagonal: apply mask
#pragma unroll
          for (int kt = 0; kt < 4; kt++)
#pragma unroll
            for (int r = 0; r < 4; r++) {
              int kv = kv0 + kt * 16 + lq * 4 + r;
              float sv = scT[kt][mi][r];
              if (kv > qrow) sv = -__builtin_inff();
              scT[kt][mi][r] = sv;
              mx = fmaxf(mx, sv);
            }
        } else {
#pragma unroll
          for (int kt = 0; kt < 4; kt++)
#pragma unroll
            for (int r = 0; r < 4; r++) mx = fmaxf(mx, scT[kt][mi][r]);
        }
        // reduce max over lq: PROVEN shfl_xor (R6 lesson: same-value "+v"
        // permlane operands get register-coalesced into a no-op swap)
        mx = fmaxf(mx, __shfl_xor(mx, 16));
        mx = fmaxf(mx, __shfl_xor(mx, 32));
        float mold = mstate[mi];
        float mnew = fmaxf(mold, mx);
        float alpha = exp2f(mold - mnew);
        float rs = 0.f;
#pragma unroll
        for (int kt = 0; kt < 4; kt++)
#pragma unroll
          for (int r = 0; r < 4; r++) {
            float p = exp2f(scT[kt][mi][r] - mnew);
            scT[kt][mi][r] = p;
            rs += p;
          }
        rs += __shfl_xor(rs, 16);
        rs += __shfl_xor(rs, 32);
        lstate[mi] = lstate[mi] * alpha + rs;
        mstate[mi] = mnew;
#pragma unroll
        for (int ni = 0; ni < 8; ni++)
#pragma unroll
          for (int r = 0; r < 4; r++) oacc[mi][ni][r] *= alpha;

        // in-register P^T redistribution (distinct-value operands: safe)
        uint D[2][4];
#pragma unroll
        for (int hb = 0; hb < 2; hb++) {
          uint s0, s1, s2, s3;
          asm("v_cvt_pk_bf16_f32 %0, %1, %2" : "=v"(s0) : "v"(scT[0][mi][2 * hb]), "v"(scT[0][mi][2 * hb + 1]));
          asm("v_cvt_pk_bf16_f32 %0, %1, %2" : "=v"(s1) : "v"(scT[1][mi][2 * hb]), "v"(scT[1][mi][2 * hb + 1]));
          asm("v_cvt_pk_bf16_f32 %0, %1, %2" : "=v"(s2) : "v"(scT[2][mi][2 * hb]), "v"(scT[2][mi][2 * hb + 1]));
          asm("v_cvt_pk_bf16_f32 %0, %1, %2" : "=v"(s3) : "v"(scT[3][mi][2 * hb]), "v"(scT[3][mi][2 * hb + 1]));
          asm("v_permlane32_swap_b32 %0, %1" : "+v"(s0), "+v"(s1));
          asm("v_permlane32_swap_b32 %0, %1" : "+v"(s2), "+v"(s3));
          asm("v_permlane16_swap_b32 %0, %1" : "+v"(s0), "+v"(s1));
          asm("v_permlane16_swap_b32 %0, %1" : "+v"(s2), "+v"(s3));
          D[0][0 + hb] = s0;   // word w: w>>1 = lq_src offset, w&1 = hb
          D[0][2 + hb] = s1;
          D[1][0 + hb] = s2;
          D[1][2 + hb] = s3;
        }
        union { uint u[4]; bf16x8 v; } u0, u1;
        u0.u[0] = D[0][0]; u0.u[1] = D[0][1]; u0.u[2] = D[0][2]; u0.u[3] = D[0][3];
        u1.u[0] = D[1][0]; u1.u[1] = D[1][1]; u1.u[2] = D[1][2]; u1.u[3] = D[1][3];
        pf[mi][0] = u0.v;
        pf[mi][1] = u1.v;
      }

      // O^T += V^T * P^T
#pragma unroll
      for (int k2 = 0; k2 < 2; k2++) {
#pragma unroll
        for (int ni = 0; ni < 8; ni++) {
          bf16x8 vf = *(const bf16x8*)(&Vts[cur][ni * 16 + lr][(k2 * 32 + lq * 8) ^ (ni << 3)]);
#pragma unroll
          for (int mi = 0; mi < 2; mi++)
            oacc[mi][ni] = __builtin_amdgcn_mfma_f32_16x16x32_bf16(vf, pf[mi][k2], oacc[mi][ni], 0, 0, 0);
        }
      }
    }  // active
    __syncthreads();
  }

  // epilogue: O /= l; lane owns q = mi*16+lr, d = ni*16+lq*4..+3 -> b64 stores
#pragma unroll
  for (int mi = 0; mi < 2; mi++) {
    float inv = 1.0f / lstate[mi];
    int q = q0 + wave * 32 + mi * 16 + lr;
    size_t base = ((size_t)b * T + q) * 2048 + (size_t)h * 128;
#pragma unroll
    for (int ni = 0; ni < 8; ni++) {
      u16x4 w;
#pragma unroll
      for (int r = 0; r < 4; r++) w[r] = f2b(oacc[mi][ni][r] * inv);
      *(u16x4*)(&O[base + ni * 16 + lq * 4]) = w;
    }
  }
}

// ---------------- launcher ----------------
extern "C" void kernel_launch(void* const* d_in, const int* in_sizes, int n_in,
                              void* d_out, int out_size, void* d_ws, size_t ws_size,
                              hipStream_t stream) {
  const float* hs   = (const float*)d_in[0];
  const float* cosp = (const float*)d_in[1];
  const float* sinp = (const float*)d_in[2];
  const float* wq   = (const float*)d_in[3];
  const float* wk   = (const float*)d_in[4];
  const float* wv   = (const float*)d_in[5];
  const float* wo   = (const float*)d_in[6];
  float* out = (float*)d_out;

  char* p = (char*)d_ws;
  ushort* hs_b = (ushort*)p; p += (size_t)8192 * 2048 * 2;
  ushort* q_b  = (ushort*)p; p += (size_t)8192 * 2048 * 2;
  ushort* k_b  = (ushort*)p; p += (size_t)8192 * 512 * 2;
  ushort* v_b  = (ushort*)p; p += (size_t)8192 * 512 * 2;
  ushort* o_b  = (ushort*)p; p += (size_t)8192 * 2048 * 2;
  ushort* wq_b = (ushort*)p; p += (size_t)2048 * 2048 * 2;
  ushort* wk_b = (ushort*)p; p += (size_t)512 * 2048 * 2;
  ushort* wv_b = (ushort*)p; p += (size_t)512 * 2048 * 2;
  ushort* wo_b = (ushort*)p; p += (size_t)2048 * 2048 * 2;

  // conversions
  cvt_kernel<<<16384, 256, 0, stream>>>(hs, hs_b, 4194304);
  cvt_kernel<<<4096, 256, 0, stream>>>(wq, wq_b, 1048576);
  cvt_kernel<<<1024, 256, 0, stream>>>(wk, wk_b, 262144);
  cvt_kernel<<<1024, 256, 0, stream>>>(wv, wv_b, 262144);
  cvt_kernel<<<4096, 256, 0, stream>>>(wo, wo_b, 1048576);

  // projections
  gemm_nt<false><<<dim3(64, 16), 256, 0, stream>>>(hs_b, wq_b, q_b, 8192, 2048, 2048);
  gemm_nt<false><<<dim3(64, 4), 256, 0, stream>>>(hs_b, wk_b, k_b, 8192, 512, 2048);
  gemm_nt<false><<<dim3(64, 4), 256, 0, stream>>>(hs_b, wv_b, v_b, 8192, 512, 2048);

  // rope (Q gets the softmax scale folded in: 1/sqrt(128) * log2(e))
  const float SC = 0.08838834764831845f * 1.4426950408889634f;
  rope_kernel<<<32768, 256, 0, stream>>>(q_b, cosp, sinp, 16, 8388608, SC);
  rope_kernel<<<8192, 256, 0, stream>>>(k_b, cosp, sinp, 4, 2097152, 1.0f);

  // attention: 256-row q tiles, 512 threads, dbuf + in-register P + V swizzle
  attn_kernel<<<dim3(8, 16, 4), 512, 0, stream>>>(q_b, k_b, v_b, o_b);

  // output projection (fp32 out)
  gemm_nt<true><<<dim3(64, 16), 256, 0, stream>>>(o_b, wo_b, out, 8192, 2048, 2048);
}

// Round 8
// 558.898 us; speedup vs baseline: 1.8822x; 1.1501x over previous
//
#include <hip/hip_runtime.h>

typedef __attribute__((ext_vector_type(8))) short bf16x8;
typedef __attribute__((ext_vector_type(4))) float f32x4;
typedef __attribute__((ext_vector_type(4))) ushort u16x4;

__device__ __forceinline__ ushort f2b(float x) {
  union { float f; uint u; } v; v.f = x;
  uint u = v.u;
  u += 0x7fffu + ((u >> 16) & 1u);
  return (ushort)(u >> 16);
}
__device__ __forceinline__ float b2f(ushort x) {
  union { uint u; float f; } v; v.u = ((uint)x) << 16;
  return v.f;
}

// async global->LDS, 16B per lane; lds base must be wave-uniform (HW scatters lane*16)
__device__ __forceinline__ void async16(const ushort* g, ushort* l) {
  __builtin_amdgcn_global_load_lds(
      (const __attribute__((address_space(1))) unsigned int*)g,
      (__attribute__((address_space(3))) unsigned int*)l, 16, 0, 0);
}

// ---------------- fp32 -> bf16 conversion ----------------
__global__ __launch_bounds__(256) void cvt_kernel(const float* __restrict__ in,
                                                  ushort* __restrict__ out, int n4) {
  int i = blockIdx.x * 256 + threadIdx.x;
  if (i >= n4) return;
  float4 v = ((const float4*)in)[i];
  ushort4 o;
  o.x = f2b(v.x); o.y = f2b(v.y); o.z = f2b(v.z); o.w = f2b(v.w);
  ((ushort4*)out)[i] = o;
}

// ---------------- RoPE (in-place on bf16), with output scale ----------------
__global__ __launch_bounds__(256) void rope_kernel(ushort* __restrict__ q,
                                                   const float* __restrict__ cs,
                                                   const float* __restrict__ sn,
                                                   int n_heads, int total, float scale) {
  int idx = blockIdx.x * 256 + threadIdx.x;
  if (idx >= total) return;
  int d = idx & 63;
  int h = (idx >> 6) % n_heads;
  int tok = idx / (64 * n_heads);
  ushort* p = q + (size_t)tok * (n_heads * 128) + h * 128 + d;
  float c = cs[(size_t)tok * 128 + d];
  float s = sn[(size_t)tok * 128 + d];
  float x1 = b2f(p[0]);
  float x2 = b2f(p[64]);
  p[0]  = f2b((x1 * c - x2 * s) * scale);
  p[64] = f2b((x2 * c + x1 * s) * scale);
}

// ---------------- NT GEMM: C[m,n] = sum_k A[m,k] * B[n,k] ----------------
// 128x128x64 tile, 4 waves (2x2 of 64x64). global_load_lds width-16 staging.
template <bool OUT_F32>
__global__ __launch_bounds__(256, 1) void gemm_nt(const ushort* __restrict__ A,
                                                  const ushort* __restrict__ B,
                                                  void* __restrict__ Cv,
                                                  int M, int N, int K) {
  __shared__ __align__(16) ushort As[128 * 64];
  __shared__ __align__(16) ushort Bs[128 * 64];
  const int tid = threadIdx.x;
  const int m0 = blockIdx.x * 128;
  const int n0 = blockIdx.y * 128;
  const int wave = tid >> 6, lane = tid & 63;
  const int wm = (wave >> 1) * 64, wn = (wave & 1) * 64;
  const int lr = lane & 15, lq = lane >> 4;

  const int rsub = lane >> 3;     // 0..7
  const int pos = lane & 7;
  const int cg = pos ^ rsub;      // swizzled global 8-ushort chunk index

  int offA[4][2], offB[4][2];
#pragma unroll
  for (int mi = 0; mi < 4; mi++)
#pragma unroll
    for (int ks = 0; ks < 2; ks++) {
      int c = ks * 4 + lq;
      int sw = (c ^ (lr & 7)) * 8;
      offA[mi][ks] = (wm + mi * 16 + lr) * 64 + sw;
      offB[mi][ks] = (wn + mi * 16 + lr) * 64 + sw;
    }

  f32x4 acc[4][4] = {};

  for (int k0 = 0; k0 < K; k0 += 64) {
#pragma unroll
    for (int i = 0; i < 4; i++) {
      int c16 = i * 4 + wave;
      int row = c16 * 8 + rsub;
      async16(A + (size_t)(m0 + row) * K + k0 + cg * 8, &As[c16 * 512]);
      async16(B + (size_t)(n0 + row) * K + k0 + cg * 8, &Bs[c16 * 512]);
    }
    // explicit drain of the LDS-DMA before the barrier (R4 lesson: races without)
    asm volatile("s_waitcnt vmcnt(0)" ::: "memory");
    __syncthreads();
#pragma unroll
    for (int ks = 0; ks < 2; ks++) {
      bf16x8 af[4], bfv[4];
#pragma unroll
      for (int mi = 0; mi < 4; mi++) af[mi] = *(const bf16x8*)(&As[offA[mi][ks]]);
#pragma unroll
      for (int ni = 0; ni < 4; ni++) bfv[ni] = *(const bf16x8*)(&Bs[offB[ni][ks]]);
#pragma unroll
      for (int mi = 0; mi < 4; mi++)
#pragma unroll
        for (int ni = 0; ni < 4; ni++)
          acc[mi][ni] = __builtin_amdgcn_mfma_f32_16x16x32_bf16(af[mi], bfv[ni], acc[mi][ni], 0, 0, 0);
    }
    __syncthreads();
  }

#pragma unroll
  for (int mi = 0; mi < 4; mi++)
#pragma unroll
    for (int ni = 0; ni < 4; ni++)
#pragma unroll
      for (int r = 0; r < 4; r++) {
        int gm = m0 + wm + mi * 16 + lq * 4 + r;
        int gn = n0 + wn + ni * 16 + lr;
        float v = acc[mi][ni][r];
        if (OUT_F32) ((float*)Cv)[(size_t)gm * N + gn] = v;
        else ((ushort*)Cv)[(size_t)gm * N + gn] = f2b(v);
      }
}

// ---------------- causal flash attention (swapped form, R8) ----------------
// R4: swapped QK^T / PV keep softmax lane-local (361 -> 260 us).
// R6/R7: in-register P^T (cvt_pk+permlane), K/V dbuf 1-barrier/iter,
//        V-write bank swizzle (245 -> 214 us).
// R8: CAUSAL PAIR SCHEDULING. R7 counters: occupancy 13.6% vs 16-wave static
// limit -> CUs average 4.4 resident waves: the wall is the qt=7 (32-iter)
// blocks running nearly alone after short blocks drain (grid was exactly
// 2 blocks/CU, work 4..32 iters, no refill). Fix: each block processes tiles
// qt0 AND 7-qt0 sequentially -> (4qt0+4)+(4(7-qt0)+4) = 36 iters, EXACTLY
// uniform across all 256 blocks = 1/CU. Zero tail; all CUs finish together.
// Uniform work also removes the need for R5's XCD remap -> natural qt order
// restores same-qt KV lockstep across heads (L2 locality, R5 cost FETCH 53->72MB).
// Phase boundary is race-free: the loop's final barrier precedes phase-1's
// first LDS write; epilogue touches only registers/global.
// Secondary (catalog m191/m218b): s_setprio(1/0) around MFMA clusters.
__global__ __launch_bounds__(512, 1) void attn_kernel(const ushort* __restrict__ Q,
                                                   const ushort* __restrict__ Kb,
                                                   const ushort* __restrict__ Vb,
                                                   ushort* __restrict__ O) {
  constexpr int T = 2048;
  __shared__ __align__(16) ushort Ks[2][64][136];   // K tiles (double-buffered)
  __shared__ __align__(16) ushort Vts[2][128][72];  // V^T tiles (swizzled cols)

  const int qt0 = blockIdx.x;             // 0..3 -> pair (qt0, 7-qt0)
  const int h = blockIdx.y, b = blockIdx.z;
  const int kvh = h >> 2;
  const int tid = threadIdx.x, wave = tid >> 6, lane = tid & 63;
  const int lr = lane & 15, lq = lane >> 4;
  const size_t qbase = (size_t)b * T * 2048 + (size_t)h * 128;
  const size_t kvbase = (size_t)b * T * 512 + (size_t)kvh * 128;

  // staging: thread owns K/V row kr, 16 consecutive ushorts at kc16 (2x uint4, coalesced)
  const int kr = tid >> 3;
  const int kc16 = (tid & 7) * 16;

  uint4 ka, kb2, va, vb2;
  auto loadkv = [&](int j) {
    const ushort* kp = Kb + kvbase + (size_t)(j * 64 + kr) * 512 + kc16;
    ka  = *(const uint4*)kp;
    kb2 = *(const uint4*)(kp + 8);
    const ushort* vp = Vb + kvbase + (size_t)(j * 64 + kr) * 512 + kc16;
    va  = *(const uint4*)vp;
    vb2 = *(const uint4*)(vp + 8);
  };
  auto writekv = [&](int bf) {
    *(uint4*)(&Ks[bf][kr][kc16])     = ka;
    *(uint4*)(&Ks[bf][kr][kc16 + 8]) = kb2;
    uint w[8] = {va.x, va.y, va.z, va.w, vb2.x, vb2.y, vb2.z, vb2.w};
#pragma unroll
    for (int i = 0; i < 8; i++) {
      int d0 = kc16 + 2 * i;
      int c0 = kr ^ ((d0 & 0x70) >> 1);       // bank swizzle (same for d0, d0+1)
      Vts[bf][d0][c0]     = (ushort)(w[i] & 0xffffu);
      Vts[bf][d0 + 1][c0] = (ushort)(w[i] >> 16);
    }
  };

  for (int phase = 0; phase < 2; ++phase) {
    const int qt = phase ? (7 - qt0) : qt0;
    const int q0 = qt * 256;
    const int jmax = 4 * qt + 3;
    const int qwmax = q0 + wave * 32 + 31;

    // Q fragments (B-operand of swapped QK^T): lane holds Q[row=..+lr][kx*32+lq*8..+7]
    bf16x8 qf[2][4];
#pragma unroll
    for (int mi = 0; mi < 2; mi++)
#pragma unroll
      for (int kx = 0; kx < 4; kx++) {
        int row = q0 + wave * 32 + mi * 16 + lr;
        qf[mi][kx] = *(const bf16x8*)(Q + qbase + (size_t)row * 2048 + kx * 32 + lq * 8);
      }

    float mstate[2], lstate[2];
    f32x4 oacc[2][8] = {};
    mstate[0] = mstate[1] = -__builtin_inff();
    lstate[0] = lstate[1] = 0.f;

    loadkv(0);
    writekv(0);
    loadkv(1);
    __syncthreads();

    for (int j = 0; j <= jmax; ++j) {
      const int cur = j & 1;
      if (j < jmax) writekv(cur ^ 1);      // stage tile j+1 (regs loaded last iter)
      if (j + 1 < jmax) loadkv(j + 2);     // issue tile j+2 loads; hide under compute
      const int kv0 = j * 64;

      if (kv0 <= qwmax) {  // wave-uniform skip of fully-masked tiles
        // S^T = K * Q^T: scT[kt][mi], kv = kt*16+lq*4+r, q = mi*16+lr
        f32x4 scT[4][2] = {};
        __builtin_amdgcn_s_setprio(1);
#pragma unroll
        for (int kx = 0; kx < 4; kx++) {
          bf16x8 kf[4];
#pragma unroll
          for (int kt = 0; kt < 4; kt++)
            kf[kt] = *(const bf16x8*)(&Ks[cur][kt * 16 + lr][kx * 32 + lq * 8]);
#pragma unroll
          for (int kt = 0; kt < 4; kt++)
#pragma unroll
            for (int mi = 0; mi < 2; mi++)
              scT[kt][mi] = __builtin_amdgcn_mfma_f32_16x16x32_bf16(kf[kt], qf[mi][kx], scT[kt][mi], 0, 0, 0);
        }
        __builtin_amdgcn_s_setprio(0);

        bf16x8 pf[2][2];
#pragma unroll
        for (int mi = 0; mi < 2; mi++) {
          const int qrow = q0 + wave * 32 + mi * 16 + lr;
          float mx = -__builtin_inff();
          if (kv0 + 63 > q0 + wave * 32 + mi * 16) {  // diagonal: apply mask
#pragma unroll
            for (int kt = 0; kt < 4; kt++)
#pragma unroll
              for (int r = 0; r < 4; r++) {
                int kv = kv0 + kt * 16 + lq * 4 + r;
                float sv = scT[kt][mi][r];
                if (kv > qrow) sv = -__builtin_inff();
                scT[kt][mi][r] = sv;
                mx = fmaxf(mx, sv);
              }
          } else {
#pragma unroll
            for (int kt = 0; kt < 4; kt++)
#pragma unroll
              for (int r = 0; r < 4; r++) mx = fmaxf(mx, scT[kt][mi][r]);
          }
          // reduce max over lq: PROVEN shfl_xor (R6 lesson: same-value "+v"
          // permlane operands get register-coalesced into a no-op swap)
          mx = fmaxf(mx, __shfl_xor(mx, 16));
          mx = fmaxf(mx, __shfl_xor(mx, 32));
          float mold = mstate[mi];
          float mnew = fmaxf(mold, mx);
          float alpha = exp2f(mold - mnew);
          float rs = 0.f;
#pragma unroll
          for (int kt = 0; kt < 4; kt++)
#pragma unroll
            for (int r = 0; r < 4; r++) {
              float p = exp2f(scT[kt][mi][r] - mnew);
              scT[kt][mi][r] = p;
              rs += p;
            }
          rs += __shfl_xor(rs, 16);
          rs += __shfl_xor(rs, 32);
          lstate[mi] = lstate[mi] * alpha + rs;
          mstate[mi] = mnew;
#pragma unroll
          for (int ni = 0; ni < 8; ni++)
#pragma unroll
            for (int r = 0; r < 4; r++) oacc[mi][ni][r] *= alpha;

          // in-register P^T redistribution (distinct-value operands: safe)
          uint D[2][4];
#pragma unroll
          for (int hb = 0; hb < 2; hb++) {
            uint s0, s1, s2, s3;
            asm("v_cvt_pk_bf16_f32 %0, %1, %2" : "=v"(s0) : "v"(scT[0][mi][2 * hb]), "v"(scT[0][mi][2 * hb + 1]));
            asm("v_cvt_pk_bf16_f32 %0, %1, %2" : "=v"(s1) : "v"(scT[1][mi][2 * hb]), "v"(scT[1][mi][2 * hb + 1]));
            asm("v_cvt_pk_bf16_f32 %0, %1, %2" : "=v"(s2) : "v"(scT[2][mi][2 * hb]), "v"(scT[2][mi][2 * hb + 1]));
            asm("v_cvt_pk_bf16_f32 %0, %1, %2" : "=v"(s3) : "v"(scT[3][mi][2 * hb]), "v"(scT[3][mi][2 * hb + 1]));
            asm("v_permlane32_swap_b32 %0, %1" : "+v"(s0), "+v"(s1));
            asm("v_permlane32_swap_b32 %0, %1" : "+v"(s2), "+v"(s3));
            asm("v_permlane16_swap_b32 %0, %1" : "+v"(s0), "+v"(s1));
            asm("v_permlane16_swap_b32 %0, %1" : "+v"(s2), "+v"(s3));
            D[0][0 + hb] = s0;   // word w: w>>1 = lq_src offset, w&1 = hb
            D[0][2 + hb] = s1;
            D[1][0 + hb] = s2;
            D[1][2 + hb] = s3;
          }
          union { uint u[4]; bf16x8 v; } u0, u1;
          u0.u[0] = D[0][0]; u0.u[1] = D[0][1]; u0.u[2] = D[0][2]; u0.u[3] = D[0][3];
          u1.u[0] = D[1][0]; u1.u[1] = D[1][1]; u1.u[2] = D[1][2]; u1.u[3] = D[1][3];
          pf[mi][0] = u0.v;
          pf[mi][1] = u1.v;
        }

        // O^T += V^T * P^T
        __builtin_amdgcn_s_setprio(1);
#pragma unroll
        for (int k2 = 0; k2 < 2; k2++) {
#pragma unroll
          for (int ni = 0; ni < 8; ni++) {
            bf16x8 vf = *(const bf16x8*)(&Vts[cur][ni * 16 + lr][(k2 * 32 + lq * 8) ^ (ni << 3)]);
#pragma unroll
            for (int mi = 0; mi < 2; mi++)
              oacc[mi][ni] = __builtin_amdgcn_mfma_f32_16x16x32_bf16(vf, pf[mi][k2], oacc[mi][ni], 0, 0, 0);
          }
        }
        __builtin_amdgcn_s_setprio(0);
      }  // active
      __syncthreads();
    }

    // epilogue: O /= l; lane owns q = mi*16+lr, d = ni*16+lq*4..+3 -> b64 stores
    // (register/global only -- no LDS hazard vs next phase's staging)
#pragma unroll
    for (int mi = 0; mi < 2; mi++) {
      float inv = 1.0f / lstate[mi];
      int q = q0 + wave * 32 + mi * 16 + lr;
      size_t base = ((size_t)b * T + q) * 2048 + (size_t)h * 128;
#pragma unroll
      for (int ni = 0; ni < 8; ni++) {
        u16x4 w;
#pragma unroll
        for (int r = 0; r < 4; r++) w[r] = f2b(oacc[mi][ni][r] * inv);
        *(u16x4*)(&O[base + ni * 16 + lq * 4]) = w;
      }
    }
  }  // phase
}

// ---------------- launcher ----------------
extern "C" void kernel_launch(void* const* d_in, const int* in_sizes, int n_in,
                              void* d_out, int out_size, void* d_ws, size_t ws_size,
                              hipStream_t stream) {
  const float* hs   = (const float*)d_in[0];
  const float* cosp = (const float*)d_in[1];
  const float* sinp = (const float*)d_in[2];
  const float* wq   = (const float*)d_in[3];
  const float* wk   = (const float*)d_in[4];
  const float* wv   = (const float*)d_in[5];
  const float* wo   = (const float*)d_in[6];
  float* out = (float*)d_out;

  char* p = (char*)d_ws;
  ushort* hs_b = (ushort*)p; p += (size_t)8192 * 2048 * 2;
  ushort* q_b  = (ushort*)p; p += (size_t)8192 * 2048 * 2;
  ushort* k_b  = (ushort*)p; p += (size_t)8192 * 512 * 2;
  ushort* v_b  = (ushort*)p; p += (size_t)8192 * 512 * 2;
  ushort* o_b  = (ushort*)p; p += (size_t)8192 * 2048 * 2;
  ushort* wq_b = (ushort*)p; p += (size_t)2048 * 2048 * 2;
  ushort* wk_b = (ushort*)p; p += (size_t)512 * 2048 * 2;
  ushort* wv_b = (ushort*)p; p += (size_t)512 * 2048 * 2;
  ushort* wo_b = (ushort*)p; p += (size_t)2048 * 2048 * 2;

  // conversions
  cvt_kernel<<<16384, 256, 0, stream>>>(hs, hs_b, 4194304);
  cvt_kernel<<<4096, 256, 0, stream>>>(wq, wq_b, 1048576);
  cvt_kernel<<<1024, 256, 0, stream>>>(wk, wk_b, 262144);
  cvt_kernel<<<1024, 256, 0, stream>>>(wv, wv_b, 262144);
  cvt_kernel<<<4096, 256, 0, stream>>>(wo, wo_b, 1048576);

  // projections
  gemm_nt<false><<<dim3(64, 16), 256, 0, stream>>>(hs_b, wq_b, q_b, 8192, 2048, 2048);
  gemm_nt<false><<<dim3(64, 4), 256, 0, stream>>>(hs_b, wk_b, k_b, 8192, 512, 2048);
  gemm_nt<false><<<dim3(64, 4), 256, 0, stream>>>(hs_b, wv_b, v_b, 8192, 512, 2048);

  // rope (Q gets the softmax scale folded in: 1/sqrt(128) * log2(e))
  const float SC = 0.08838834764831845f * 1.4426950408889634f;
  rope_kernel<<<32768, 256, 0, stream>>>(q_b, cosp, sinp, 16, 8388608, SC);
  rope_kernel<<<8192, 256, 0, stream>>>(k_b, cosp, sinp, 4, 2097152, 1.0f);

  // attention: paired causal tiles (qt0, 7-qt0), 256 blocks = 1/CU, uniform 36 iters
  attn_kernel<<<dim3(4, 16, 4), 512, 0, stream>>>(q_b, k_b, v_b, o_b);

  // output projection (fp32 out)
  gemm_nt<true><<<dim3(64, 16), 256, 0, stream>>>(o_b, wo_b, out, 8192, 2048, 2048);
}

// Round 9
// 517.302 us; speedup vs baseline: 2.0336x; 1.0804x over previous
//
#include <hip/hip_runtime.h>

typedef __attribute__((ext_vector_type(8))) short bf16x8;
typedef __attribute__((ext_vector_type(4))) float f32x4;
typedef __attribute__((ext_vector_type(4))) ushort u16x4;

__device__ __forceinline__ ushort f2b(float x) {
  union { float f; uint u; } v; v.f = x;
  uint u = v.u;
  u += 0x7fffu + ((u >> 16) & 1u);
  return (ushort)(u >> 16);
}
__device__ __forceinline__ float b2f(ushort x) {
  union { uint u; float f; } v; v.u = ((uint)x) << 16;
  return v.f;
}

// async global->LDS, 16B per lane; lds base must be wave-uniform (HW scatters lane*16)
__device__ __forceinline__ void async16(const ushort* g, ushort* l) {
  __builtin_amdgcn_global_load_lds(
      (const __attribute__((address_space(1))) unsigned int*)g,
      (__attribute__((address_space(3))) unsigned int*)l, 16, 0, 0);
}

// ---------------- fp32 -> bf16 conversion, all 5 tensors in ONE launch ----------------
// R9: 5 cvt launches -> 1 (launch gaps were serialized on the single stream).
__global__ __launch_bounds__(256) void cvt_all(const float* __restrict__ hs,
                                               const float* __restrict__ wq,
                                               const float* __restrict__ wk,
                                               const float* __restrict__ wv,
                                               const float* __restrict__ wo,
                                               ushort* __restrict__ hs_b,
                                               ushort* __restrict__ wq_b,
                                               ushort* __restrict__ wk_b,
                                               ushort* __restrict__ wv_b,
                                               ushort* __restrict__ wo_b) {
  int i = blockIdx.x * 256 + threadIdx.x;
  const float* src; ushort* dst; int base;
  if (i < 4194304)      { src = hs; dst = hs_b; base = 0; }
  else if (i < 5242880) { src = wq; dst = wq_b; base = 4194304; }
  else if (i < 5505024) { src = wk; dst = wk_b; base = 5242880; }
  else if (i < 5767168) { src = wv; dst = wv_b; base = 5505024; }
  else if (i < 6815744) { src = wo; dst = wo_b; base = 5767168; }
  else return;
  int j = i - base;
  float4 v = ((const float4*)src)[j];
  ushort4 o;
  o.x = f2b(v.x); o.y = f2b(v.y); o.z = f2b(v.z); o.w = f2b(v.w);
  ((ushort4*)dst)[j] = o;
}

// ---------------- RoPE for Q and K in ONE launch ----------------
// Q gets the softmax scale 1/sqrt(128)*log2(e) folded in.
__global__ __launch_bounds__(256) void rope_all(ushort* __restrict__ q,
                                                ushort* __restrict__ k,
                                                const float* __restrict__ cs,
                                                const float* __restrict__ sn,
                                                float qscale) {
  int idx = blockIdx.x * 256 + threadIdx.x;
  ushort* p; int d, tok; float scale;
  if (idx < 8388608) {            // Q: 8192 tok x 16 heads x 64 pairs
    d = idx & 63;
    int h = (idx >> 6) & 15;
    tok = idx >> 10;              // /(64*16)
    p = q + (size_t)tok * 2048 + h * 128 + d;
    scale = qscale;
  } else {                        // K: 8192 tok x 4 heads x 64 pairs
    int i2 = idx - 8388608;
    d = i2 & 63;
    int h = (i2 >> 6) & 3;
    tok = i2 >> 8;                // /(64*4)
    p = k + (size_t)tok * 512 + h * 128 + d;
    scale = 1.0f;
  }
  float c = cs[(size_t)tok * 128 + d];
  float s = sn[(size_t)tok * 128 + d];
  float x1 = b2f(p[0]);
  float x2 = b2f(p[64]);
  p[0]  = f2b((x1 * c - x2 * s) * scale);
  p[64] = f2b((x2 * c + x1 * s) * scale);
}

// ---------------- NT GEMM: C[m,n] = sum_k A[m,k] * B[n,k] ----------------
// 128x128x64 tile, 4 waves (2x2 of 64x64). global_load_lds width-16 staging.
// Used for the O-projection (fp32 out).
template <bool OUT_F32>
__global__ __launch_bounds__(256, 1) void gemm_nt(const ushort* __restrict__ A,
                                                  const ushort* __restrict__ B,
                                                  void* __restrict__ Cv,
                                                  int M, int N, int K) {
  __shared__ __align__(16) ushort As[128 * 64];
  __shared__ __align__(16) ushort Bs[128 * 64];
  const int tid = threadIdx.x;
  const int m0 = blockIdx.x * 128;
  const int n0 = blockIdx.y * 128;
  const int wave = tid >> 6, lane = tid & 63;
  const int wm = (wave >> 1) * 64, wn = (wave & 1) * 64;
  const int lr = lane & 15, lq = lane >> 4;

  const int rsub = lane >> 3;     // 0..7
  const int pos = lane & 7;
  const int cg = pos ^ rsub;      // swizzled global 8-ushort chunk index

  int offA[4][2], offB[4][2];
#pragma unroll
  for (int mi = 0; mi < 4; mi++)
#pragma unroll
    for (int ks = 0; ks < 2; ks++) {
      int c = ks * 4 + lq;
      int sw = (c ^ (lr & 7)) * 8;
      offA[mi][ks] = (wm + mi * 16 + lr) * 64 + sw;
      offB[mi][ks] = (wn + mi * 16 + lr) * 64 + sw;
    }

  f32x4 acc[4][4] = {};

  for (int k0 = 0; k0 < K; k0 += 64) {
#pragma unroll
    for (int i = 0; i < 4; i++) {
      int c16 = i * 4 + wave;
      int row = c16 * 8 + rsub;
      async16(A + (size_t)(m0 + row) * K + k0 + cg * 8, &As[c16 * 512]);
      async16(B + (size_t)(n0 + row) * K + k0 + cg * 8, &Bs[c16 * 512]);
    }
    // explicit drain of the LDS-DMA before the barrier (R4 lesson: races without)
    asm volatile("s_waitcnt vmcnt(0)" ::: "memory");
    __syncthreads();
#pragma unroll
    for (int ks = 0; ks < 2; ks++) {
      bf16x8 af[4], bfv[4];
#pragma unroll
      for (int mi = 0; mi < 4; mi++) af[mi] = *(const bf16x8*)(&As[offA[mi][ks]]);
#pragma unroll
      for (int ni = 0; ni < 4; ni++) bfv[ni] = *(const bf16x8*)(&Bs[offB[ni][ks]]);
#pragma unroll
      for (int mi = 0; mi < 4; mi++)
#pragma unroll
        for (int ni = 0; ni < 4; ni++)
          acc[mi][ni] = __builtin_amdgcn_mfma_f32_16x16x32_bf16(af[mi], bfv[ni], acc[mi][ni], 0, 0, 0);
    }
    __syncthreads();
  }

#pragma unroll
  for (int mi = 0; mi < 4; mi++)
#pragma unroll
    for (int ni = 0; ni < 4; ni++)
#pragma unroll
      for (int r = 0; r < 4; r++) {
        int gm = m0 + wm + mi * 16 + lq * 4 + r;
        int gn = n0 + wn + ni * 16 + lr;
        float v = acc[mi][ni][r];
        if (OUT_F32) ((float*)Cv)[(size_t)gm * N + gn] = v;
        else ((ushort*)Cv)[(size_t)gm * N + gn] = f2b(v);
      }
}

// ---------------- fused Q/K/V projection GEMM ----------------
// R9: wq_b/wk_b/wv_b are CONTIGUOUS in the workspace -> B is one 3072x2048
// matrix. Previously K-proj and V-proj each ran at 256 blocks = 1 block/CU
// (zero inter-block overlap of the vmcnt(0) drain), serialized after Q-proj.
// Fused: grid (64,24) = 1536 blocks (~3/CU resident) -> K/V work overlaps.
// Output routing is block-uniform: by<16 -> q_b (stride 2048),
// by<20 -> k_b (stride 512), else v_b (stride 512).
__global__ __launch_bounds__(256, 1) void gemm_qkv(const ushort* __restrict__ A,
                                                   const ushort* __restrict__ B,
                                                   ushort* __restrict__ Cq,
                                                   ushort* __restrict__ Ck,
                                                   ushort* __restrict__ Cvp,
                                                   int K) {
  __shared__ __align__(16) ushort As[128 * 64];
  __shared__ __align__(16) ushort Bs[128 * 64];
  const int tid = threadIdx.x;
  const int m0 = blockIdx.x * 128;
  const int n0 = blockIdx.y * 128;
  const int wave = tid >> 6, lane = tid & 63;
  const int wm = (wave >> 1) * 64, wn = (wave & 1) * 64;
  const int lr = lane & 15, lq = lane >> 4;

  const int rsub = lane >> 3;
  const int pos = lane & 7;
  const int cg = pos ^ rsub;

  int offA[4][2], offB[4][2];
#pragma unroll
  for (int mi = 0; mi < 4; mi++)
#pragma unroll
    for (int ks = 0; ks < 2; ks++) {
      int c = ks * 4 + lq;
      int sw = (c ^ (lr & 7)) * 8;
      offA[mi][ks] = (wm + mi * 16 + lr) * 64 + sw;
      offB[mi][ks] = (wn + mi * 16 + lr) * 64 + sw;
    }

  f32x4 acc[4][4] = {};

  for (int k0 = 0; k0 < K; k0 += 64) {
#pragma unroll
    for (int i = 0; i < 4; i++) {
      int c16 = i * 4 + wave;
      int row = c16 * 8 + rsub;
      async16(A + (size_t)(m0 + row) * K + k0 + cg * 8, &As[c16 * 512]);
      async16(B + (size_t)(n0 + row) * K + k0 + cg * 8, &Bs[c16 * 512]);
    }
    asm volatile("s_waitcnt vmcnt(0)" ::: "memory");
    __syncthreads();
#pragma unroll
    for (int ks = 0; ks < 2; ks++) {
      bf16x8 af[4], bfv[4];
#pragma unroll
      for (int mi = 0; mi < 4; mi++) af[mi] = *(const bf16x8*)(&As[offA[mi][ks]]);
#pragma unroll
      for (int ni = 0; ni < 4; ni++) bfv[ni] = *(const bf16x8*)(&Bs[offB[ni][ks]]);
#pragma unroll
      for (int mi = 0; mi < 4; mi++)
#pragma unroll
        for (int ni = 0; ni < 4; ni++)
          acc[mi][ni] = __builtin_amdgcn_mfma_f32_16x16x32_bf16(af[mi], bfv[ni], acc[mi][ni], 0, 0, 0);
    }
    __syncthreads();
  }

  // block-uniform output select
  ushort* Co; int Nc, nc0;
  if (n0 < 2048)      { Co = Cq;  Nc = 2048; nc0 = n0; }
  else if (n0 < 2560) { Co = Ck;  Nc = 512;  nc0 = n0 - 2048; }
  else                { Co = Cvp; Nc = 512;  nc0 = n0 - 2560; }

#pragma unroll
  for (int mi = 0; mi < 4; mi++)
#pragma unroll
    for (int ni = 0; ni < 4; ni++)
#pragma unroll
      for (int r = 0; r < 4; r++) {
        int gm = m0 + wm + mi * 16 + lq * 4 + r;
        int gn = nc0 + wn + ni * 16 + lr;
        Co[(size_t)gm * Nc + gn] = f2b(acc[mi][ni][r]);
      }
}

// ---------------- causal flash attention (swapped form, R9) ----------------
// R4: swapped QK^T / PV keep softmax lane-local (361 -> 260 us).
// R6/R7: in-register P^T (cvt_pk+permlane), K/V dbuf 1-barrier/iter,
//        V-write bank swizzle (245 -> 214 us).
// R8: causal pair scheduling -- block does tiles (qt0, 7-qt0) = uniform 36
//     iters, 256 blocks = 1/CU, zero tail (214 -> 144 us, occupancy 13.6->22.3).
// R9: T13 defer-rescale (catalog m214v23/m239): skip the 64-reg oacc rescale
//     when __all(mx <= mold + 8) (log2 domain; P bounded by 2^8 -- bf16-safe,
//     absmax headroom 4.8x). Safe vs -inf: every processed tile has
//     kv0 <= qrow for all rows (64|kv0 alignment), so mx is always finite.
__global__ __launch_bounds__(512, 1) void attn_kernel(const ushort* __restrict__ Q,
                                                   const ushort* __restrict__ Kb,
                                                   const ushort* __restrict__ Vb,
                                                   ushort* __restrict__ O) {
  constexpr int T = 2048;
  __shared__ __align__(16) ushort Ks[2][64][136];   // K tiles (double-buffered)
  __shared__ __align__(16) ushort Vts[2][128][72];  // V^T tiles (swizzled cols)

  const int qt0 = blockIdx.x;             // 0..3 -> pair (qt0, 7-qt0)
  const int h = blockIdx.y, b = blockIdx.z;
  const int kvh = h >> 2;
  const int tid = threadIdx.x, wave = tid >> 6, lane = tid & 63;
  const int lr = lane & 15, lq = lane >> 4;
  const size_t qbase = (size_t)b * T * 2048 + (size_t)h * 128;
  const size_t kvbase = (size_t)b * T * 512 + (size_t)kvh * 128;

  // staging: thread owns K/V row kr, 16 consecutive ushorts at kc16 (2x uint4, coalesced)
  const int kr = tid >> 3;
  const int kc16 = (tid & 7) * 16;

  uint4 ka, kb2, va, vb2;
  auto loadkv = [&](int j) {
    const ushort* kp = Kb + kvbase + (size_t)(j * 64 + kr) * 512 + kc16;
    ka  = *(const uint4*)kp;
    kb2 = *(const uint4*)(kp + 8);
    const ushort* vp = Vb + kvbase + (size_t)(j * 64 + kr) * 512 + kc16;
    va  = *(const uint4*)vp;
    vb2 = *(const uint4*)(vp + 8);
  };
  auto writekv = [&](int bf) {
    *(uint4*)(&Ks[bf][kr][kc16])     = ka;
    *(uint4*)(&Ks[bf][kr][kc16 + 8]) = kb2;
    uint w[8] = {va.x, va.y, va.z, va.w, vb2.x, vb2.y, vb2.z, vb2.w};
#pragma unroll
    for (int i = 0; i < 8; i++) {
      int d0 = kc16 + 2 * i;
      int c0 = kr ^ ((d0 & 0x70) >> 1);       // bank swizzle (same for d0, d0+1)
      Vts[bf][d0][c0]     = (ushort)(w[i] & 0xffffu);
      Vts[bf][d0 + 1][c0] = (ushort)(w[i] >> 16);
    }
  };

  for (int phase = 0; phase < 2; ++phase) {
    const int qt = phase ? (7 - qt0) : qt0;
    const int q0 = qt * 256;
    const int jmax = 4 * qt + 3;
    const int qwmax = q0 + wave * 32 + 31;

    // Q fragments (B-operand of swapped QK^T): lane holds Q[row=..+lr][kx*32+lq*8..+7]
    bf16x8 qf[2][4];
#pragma unroll
    for (int mi = 0; mi < 2; mi++)
#pragma unroll
      for (int kx = 0; kx < 4; kx++) {
        int row = q0 + wave * 32 + mi * 16 + lr;
        qf[mi][kx] = *(const bf16x8*)(Q + qbase + (size_t)row * 2048 + kx * 32 + lq * 8);
      }

    float mstate[2], lstate[2];
    f32x4 oacc[2][8] = {};
    mstate[0] = mstate[1] = -__builtin_inff();
    lstate[0] = lstate[1] = 0.f;

    loadkv(0);
    writekv(0);
    loadkv(1);
    __syncthreads();

    for (int j = 0; j <= jmax; ++j) {
      const int cur = j & 1;
      if (j < jmax) writekv(cur ^ 1);      // stage tile j+1 (regs loaded last iter)
      if (j + 1 < jmax) loadkv(j + 2);     // issue tile j+2 loads; hide under compute
      const int kv0 = j * 64;

      if (kv0 <= qwmax) {  // wave-uniform skip of fully-masked tiles
        // S^T = K * Q^T: scT[kt][mi], kv = kt*16+lq*4+r, q = mi*16+lr
        f32x4 scT[4][2] = {};
        __builtin_amdgcn_s_setprio(1);
#pragma unroll
        for (int kx = 0; kx < 4; kx++) {
          bf16x8 kf[4];
#pragma unroll
          for (int kt = 0; kt < 4; kt++)
            kf[kt] = *(const bf16x8*)(&Ks[cur][kt * 16 + lr][kx * 32 + lq * 8]);
#pragma unroll
          for (int kt = 0; kt < 4; kt++)
#pragma unroll
            for (int mi = 0; mi < 2; mi++)
              scT[kt][mi] = __builtin_amdgcn_mfma_f32_16x16x32_bf16(kf[kt], qf[mi][kx], scT[kt][mi], 0, 0, 0);
        }
        __builtin_amdgcn_s_setprio(0);

        bf16x8 pf[2][2];
#pragma unroll
        for (int mi = 0; mi < 2; mi++) {
          const int qrow = q0 + wave * 32 + mi * 16 + lr;
          float mx = -__builtin_inff();
          if (kv0 + 63 > q0 + wave * 32 + mi * 16) {  // diagonal: apply mask
#pragma unroll
            for (int kt = 0; kt < 4; kt++)
#pragma unroll
              for (int r = 0; r < 4; r++) {
                int kv = kv0 + kt * 16 + lq * 4 + r;
                float sv = scT[kt][mi][r];
                if (kv > qrow) sv = -__builtin_inff();
                scT[kt][mi][r] = sv;
                mx = fmaxf(mx, sv);
              }
          } else {
#pragma unroll
            for (int kt = 0; kt < 4; kt++)
#pragma unroll
              for (int r = 0; r < 4; r++) mx = fmaxf(mx, scT[kt][mi][r]);
          }
          // reduce max over lq: PROVEN shfl_xor (R6 lesson: same-value "+v"
          // permlane operands get register-coalesced into a no-op swap)
          mx = fmaxf(mx, __shfl_xor(mx, 16));
          mx = fmaxf(mx, __shfl_xor(mx, 32));
          float mold = mstate[mi];
          float mnew = fmaxf(mold, mx);
          // T13 defer-rescale: only pay the 64-reg rescale when max grew >8
          if (!__all(mx <= mold + 8.0f)) {
            float alpha = exp2f(mold - mnew);
            lstate[mi] *= alpha;
#pragma unroll
            for (int ni = 0; ni < 8; ni++)
#pragma unroll
              for (int r = 0; r < 4; r++) oacc[mi][ni][r] *= alpha;
            mstate[mi] = mnew;
          } else {
            mnew = mold;   // keep old max; P bounded by 2^8
          }
          float rs = 0.f;
#pragma unroll
          for (int kt = 0; kt < 4; kt++)
#pragma unroll
            for (int r = 0; r < 4; r++) {
              float p = exp2f(scT[kt][mi][r] - mnew);
              scT[kt][mi][r] = p;
              rs += p;
            }
          rs += __shfl_xor(rs, 16);
          rs += __shfl_xor(rs, 32);
          lstate[mi] += rs;

          // in-register P^T redistribution (distinct-value operands: safe)
          uint D[2][4];
#pragma unroll
          for (int hb = 0; hb < 2; hb++) {
            uint s0, s1, s2, s3;
            asm("v_cvt_pk_bf16_f32 %0, %1, %2" : "=v"(s0) : "v"(scT[0][mi][2 * hb]), "v"(scT[0][mi][2 * hb + 1]));
            asm("v_cvt_pk_bf16_f32 %0, %1, %2" : "=v"(s1) : "v"(scT[1][mi][2 * hb]), "v"(scT[1][mi][2 * hb + 1]));
            asm("v_cvt_pk_bf16_f32 %0, %1, %2" : "=v"(s2) : "v"(scT[2][mi][2 * hb]), "v"(scT[2][mi][2 * hb + 1]));
            asm("v_cvt_pk_bf16_f32 %0, %1, %2" : "=v"(s3) : "v"(scT[3][mi][2 * hb]), "v"(scT[3][mi][2 * hb + 1]));
            asm("v_permlane32_swap_b32 %0, %1" : "+v"(s0), "+v"(s1));
            asm("v_permlane32_swap_b32 %0, %1" : "+v"(s2), "+v"(s3));
            asm("v_permlane16_swap_b32 %0, %1" : "+v"(s0), "+v"(s1));
            asm("v_permlane16_swap_b32 %0, %1" : "+v"(s2), "+v"(s3));
            D[0][0 + hb] = s0;   // word w: w>>1 = lq_src offset, w&1 = hb
            D[0][2 + hb] = s1;
            D[1][0 + hb] = s2;
            D[1][2 + hb] = s3;
          }
          union { uint u[4]; bf16x8 v; } u0, u1;
          u0.u[0] = D[0][0]; u0.u[1] = D[0][1]; u0.u[2] = D[0][2]; u0.u[3] = D[0][3];
          u1.u[0] = D[1][0]; u1.u[1] = D[1][1]; u1.u[2] = D[1][2]; u1.u[3] = D[1][3];
          pf[mi][0] = u0.v;
          pf[mi][1] = u1.v;
        }

        // O^T += V^T * P^T
        __builtin_amdgcn_s_setprio(1);
#pragma unroll
        for (int k2 = 0; k2 < 2; k2++) {
#pragma unroll
          for (int ni = 0; ni < 8; ni++) {
            bf16x8 vf = *(const bf16x8*)(&Vts[cur][ni * 16 + lr][(k2 * 32 + lq * 8) ^ (ni << 3)]);
#pragma unroll
            for (int mi = 0; mi < 2; mi++)
              oacc[mi][ni] = __builtin_amdgcn_mfma_f32_16x16x32_bf16(vf, pf[mi][k2], oacc[mi][ni], 0, 0, 0);
          }
        }
        __builtin_amdgcn_s_setprio(0);
      }  // active
      __syncthreads();
    }

    // epilogue: O /= l; lane owns q = mi*16+lr, d = ni*16+lq*4..+3 -> b64 stores
    // (register/global only -- no LDS hazard vs next phase's staging)
#pragma unroll
    for (int mi = 0; mi < 2; mi++) {
      float inv = 1.0f / lstate[mi];
      int q = q0 + wave * 32 + mi * 16 + lr;
      size_t base = ((size_t)b * T + q) * 2048 + (size_t)h * 128;
#pragma unroll
      for (int ni = 0; ni < 8; ni++) {
        u16x4 w;
#pragma unroll
        for (int r = 0; r < 4; r++) w[r] = f2b(oacc[mi][ni][r] * inv);
        *(u16x4*)(&O[base + ni * 16 + lq * 4]) = w;
      }
    }
  }  // phase
}

// ---------------- launcher ----------------
extern "C" void kernel_launch(void* const* d_in, const int* in_sizes, int n_in,
                              void* d_out, int out_size, void* d_ws, size_t ws_size,
                              hipStream_t stream) {
  const float* hs   = (const float*)d_in[0];
  const float* cosp = (const float*)d_in[1];
  const float* sinp = (const float*)d_in[2];
  const float* wq   = (const float*)d_in[3];
  const float* wk   = (const float*)d_in[4];
  const float* wv   = (const float*)d_in[5];
  const float* wo   = (const float*)d_in[6];
  float* out = (float*)d_out;

  char* p = (char*)d_ws;
  ushort* hs_b = (ushort*)p; p += (size_t)8192 * 2048 * 2;
  ushort* q_b  = (ushort*)p; p += (size_t)8192 * 2048 * 2;
  ushort* k_b  = (ushort*)p; p += (size_t)8192 * 512 * 2;
  ushort* v_b  = (ushort*)p; p += (size_t)8192 * 512 * 2;
  ushort* o_b  = (ushort*)p; p += (size_t)8192 * 2048 * 2;
  // NOTE: wq_b/wk_b/wv_b MUST stay contiguous (gemm_qkv treats them as one
  // 3072x2048 B matrix).
  ushort* wq_b = (ushort*)p; p += (size_t)2048 * 2048 * 2;
  ushort* wk_b = (ushort*)p; p += (size_t)512 * 2048 * 2;
  ushort* wv_b = (ushort*)p; p += (size_t)512 * 2048 * 2;
  ushort* wo_b = (ushort*)p; p += (size_t)2048 * 2048 * 2;

  // all conversions in one launch (6815744 float4s)
  cvt_all<<<26624, 256, 0, stream>>>(hs, wq, wk, wv, wo, hs_b, wq_b, wk_b, wv_b, wo_b);

  // fused Q/K/V projection: C[8192x3072] = hs_b @ [wq;wk;wv]^T
  gemm_qkv<<<dim3(64, 24), 256, 0, stream>>>(hs_b, wq_b, q_b, k_b, v_b, 2048);

  // rope for Q (scaled) and K in one launch
  const float SC = 0.08838834764831845f * 1.4426950408889634f;
  rope_all<<<40960, 256, 0, stream>>>(q_b, k_b, cosp, sinp, SC);

  // attention: paired causal tiles (qt0, 7-qt0), 256 blocks = 1/CU, uniform 36 iters
  attn_kernel<<<dim3(4, 16, 4), 512, 0, stream>>>(q_b, k_b, v_b, o_b);

  // output projection (fp32 out)
  gemm_nt<true><<<dim3(64, 16), 256, 0, stream>>>(o_b, wo_b, out, 8192, 2048, 2048);
}